// Round 4
// baseline (2408.623 us; speedup 1.0000x reference)
//
#include <hip/hip_runtime.h>
#include <hip/hip_bf16.h>
#include <stdint.h>
#include <float.h>

// B=64, E=H=512, V=32000, T=20 (lengths[0]=T so max(lengths)==20 always)
#define BB 64
#define EE 512
#define HH 512
#define VV 32000
#define TT 20

// ---------------- threefry2x32 (JAX-exact, 20 rounds) ----------------
__device__ __host__ __forceinline__ void tf2x32(uint32_t k0, uint32_t k1, uint32_t x0, uint32_t x1,
                                                uint32_t& o0, uint32_t& o1) {
  const uint32_t k2 = k0 ^ k1 ^ 0x1BD11BDAu;
  x0 += k0; x1 += k1;
#define RND(R) { x0 += x1; x1 = (x1 << R) | (x1 >> (32 - R)); x1 ^= x0; }
  RND(13) RND(15) RND(26) RND(6)
  x0 += k1; x1 += k2 + 1u;
  RND(17) RND(29) RND(16) RND(24)
  x0 += k2; x1 += k0 + 2u;
  RND(13) RND(15) RND(26) RND(6)
  x0 += k0; x1 += k1 + 3u;
  RND(17) RND(29) RND(16) RND(24)
  x0 += k1; x1 += k2 + 4u;
  RND(13) RND(15) RND(26) RND(6)
  x0 += k2; x1 += k0 + 5u;
#undef RND
  o0 = x0; o1 = x1;
}

// partitionable-threefry (JAX >= 0.5 default) random bits for flat index idx under
// step key (k1t,k2t): bits = o0 ^ o1 of threefry(key, (hi=0, lo=idx));
// uniform = bitcast(0x3f800000|bits>>9)-1, 0 -> tiny (gumbel's minval=tiny clamp);
// gumbel = -log(-log(u))
__device__ __forceinline__ float gumbel_for(uint32_t k1t, uint32_t k2t, uint32_t idx) {
  uint32_t o0, o1; tf2x32(k1t, k2t, 0u, idx, o0, o1);
  uint32_t bits = o0 ^ o1;
  uint32_t mant = bits >> 9;
  float f = __uint_as_float(0x3f800000u | mant) - 1.0f;
  float u = mant ? f : 1.1754943508222875e-38f;
  return -logf(-logf(u));
}

struct Part { float bv; int bix; float blog; float m; float s; };

__device__ __forceinline__ void part_combine(Part& P, const Part& Q) {
  if (Q.bv > P.bv || (Q.bv == P.bv && Q.bix < P.bix)) { P.bv = Q.bv; P.bix = Q.bix; P.blog = Q.blog; }
  if (Q.m > P.m) { P.s = P.s * expf(P.m - Q.m) + Q.s; P.m = Q.m; }
  else           { P.s += Q.s * expf(Q.m - P.m); }
}

// ---------------- K0: init ----------------
__global__ __launch_bounds__(256) void k_init(float* __restrict__ hA, float* __restrict__ cT,
                                              int* __restrict__ done) {
  int i = blockIdx.x * 256 + threadIdx.x;
  if (i < HH * BB) { hA[i] = 0.f; cT[i] = 0.f; }
  if (i < BB) done[i] = 0;
}

// ---------------- K1: fused gates GEMM + LSTM cell update ----------------
__global__ __launch_bounds__(256) void k_cell(const float* __restrict__ xin,   // [64][512] b-major
                                              const float* __restrict__ hin,   // [512][64] k-major
                                              const float* __restrict__ Wih,
                                              const float* __restrict__ Whh,
                                              const float* __restrict__ bih,
                                              const float* __restrict__ bhh,
                                              float* __restrict__ cT,          // [512][64] in-place
                                              float* __restrict__ hout) {      // [512][64]
  const int jt = blockIdx.x;
  const int tx = threadIdx.x;
  __shared__ float a[64][64];     // [kk][b]
  __shared__ float wj[64][34];    // [kk][jslot] padded
  const int b0 = (tx & 15) * 4;
  const int r0 = (tx >> 4) * 2;   // j-slot pair
  float acc[2][4] = {};
  for (int kc = 0; kc < 16; ++kc) {
    const int kg = kc * 64;
    if (kg < 512) {
      #pragma unroll
      for (int r = 0; r < 4; ++r) {
        int fi = r * 256 + tx;
        int b = fi >> 4, k4 = (fi & 15) * 4;
        const float4 v = *(const float4*)(xin + b * EE + kg + k4);
        a[k4 + 0][b] = v.x; a[k4 + 1][b] = v.y; a[k4 + 2][b] = v.z; a[k4 + 3][b] = v.w;
      }
    } else {
      #pragma unroll
      for (int r = 0; r < 4; ++r) {
        int fi = r * 256 + tx;
        int kk = fi >> 4, b4 = (fi & 15) * 4;
        *(float4*)(&a[kk][b4]) = *(const float4*)(hin + (kg - 512 + kk) * BB + b4);
      }
    }
    {
      const float* Wsrc = (kg < 512) ? Wih : Whh;
      const int kcol = kg & 511;
      #pragma unroll
      for (int r = 0; r < 2; ++r) {
        int fi = r * 256 + tx;
        int slot = fi >> 4, k4 = (fi & 15) * 4;
        int g = slot >> 3, q = slot & 7;
        const float4 v = *(const float4*)(Wsrc + (size_t)(g * 512 + jt * 8 + q) * 512 + kcol + k4);
        wj[k4 + 0][slot] = v.x; wj[k4 + 1][slot] = v.y;
        wj[k4 + 2][slot] = v.z; wj[k4 + 3][slot] = v.w;
      }
    }
    __syncthreads();
    #pragma unroll 8
    for (int kk = 0; kk < 64; ++kk) {
      const float4 av = *(const float4*)(&a[kk][b0]);
      const float w0 = wj[kk][r0], w1 = wj[kk][r0 + 1];
      acc[0][0] = fmaf(w0, av.x, acc[0][0]); acc[0][1] = fmaf(w0, av.y, acc[0][1]);
      acc[0][2] = fmaf(w0, av.z, acc[0][2]); acc[0][3] = fmaf(w0, av.w, acc[0][3]);
      acc[1][0] = fmaf(w1, av.x, acc[1][0]); acc[1][1] = fmaf(w1, av.y, acc[1][1]);
      acc[1][2] = fmaf(w1, av.z, acc[1][2]); acc[1][3] = fmaf(w1, av.w, acc[1][3]);
    }
    __syncthreads();
  }
  float* gl = &a[0][0];           // [32][64]
  *(float4*)(gl + (r0 + 0) * 64 + b0) = make_float4(acc[0][0], acc[0][1], acc[0][2], acc[0][3]);
  *(float4*)(gl + (r0 + 1) * 64 + b0) = make_float4(acc[1][0], acc[1][1], acc[1][2], acc[1][3]);
  __syncthreads();
  #pragma unroll
  for (int r = 0; r < 2; ++r) {
    const int idx = r * 256 + tx;     // 0..511 -> (q, b)
    const int q = idx >> 6, b = idx & 63;
    const int jb = jt * 8 + q;
    const float gi = gl[(0 * 8 + q) * 64 + b] + bih[jb]        + bhh[jb];
    const float gf = gl[(1 * 8 + q) * 64 + b] + bih[512 + jb]  + bhh[512 + jb];
    const float gg = gl[(2 * 8 + q) * 64 + b] + bih[1024 + jb] + bhh[1024 + jb];
    const float go = gl[(3 * 8 + q) * 64 + b] + bih[1536 + jb] + bhh[1536 + jb];
    const float ig = 1.f / (1.f + expf(-gi));
    const float fg = 1.f / (1.f + expf(-gf));
    const float g  = tanhf(gg);
    const float og = 1.f / (1.f + expf(-go));
    const float c = fg * cT[jb * BB + b] + ig * g;
    cT[jb * BB + b] = c;
    hout[jb * BB + b] = og * tanhf(c);
  }
}

// ---------------- K2: logits GEMM + gumbel + per-tile partials ----------------
__global__ __launch_bounds__(256) void k_logits(const float* __restrict__ hT,
                                                const float* __restrict__ LW,
                                                const float* __restrict__ lb,
                                                uint32_t k1t, uint32_t k2t,
                                                float4* __restrict__ pf4,
                                                int* __restrict__ pidx) {
  const int vt = blockIdx.x;       // 0..249
  const int tx = threadIdx.x;
  __shared__ float smem[4096 + 64 * 132];
  float* hs = smem;
  float* wT = smem + 4096;
  const int vi = (tx & 31) * 4;    // 0..124
  const int bi = (tx >> 5) * 8;    // 0..56
  float acc[8][4] = {};
  for (int kt = 0; kt < 8; ++kt) {
    #pragma unroll
    for (int r = 0; r < 4; ++r) {
      int fi = r * 256 + tx;
      int row = fi >> 4, c4 = (fi & 15) * 4;
      *(float4*)(hs + (row << 6) + c4) = *(const float4*)(hT + (kt * 64 + row) * BB + c4);
    }
    #pragma unroll
    for (int r = 0; r < 8; ++r) {
      int fi = r * 256 + tx;
      int v = fi >> 4, k4 = (fi & 15) * 4;
      const float4 w = *(const float4*)(LW + (size_t)(vt * 128 + v) * HH + kt * 64 + k4);
      wT[(k4 + 0) * 132 + v] = w.x; wT[(k4 + 1) * 132 + v] = w.y;
      wT[(k4 + 2) * 132 + v] = w.z; wT[(k4 + 3) * 132 + v] = w.w;
    }
    __syncthreads();
    #pragma unroll 4
    for (int kk = 0; kk < 64; ++kk) {
      const float4 w4 = *(const float4*)(wT + kk * 132 + vi);
      const float4 h0 = *(const float4*)(hs + (kk << 6) + bi);
      const float4 h1 = *(const float4*)(hs + (kk << 6) + bi + 4);
      const float wvx[4] = {w4.x, w4.y, w4.z, w4.w};
      const float hvx[8] = {h0.x, h0.y, h0.z, h0.w, h1.x, h1.y, h1.z, h1.w};
      #pragma unroll
      for (int bb = 0; bb < 8; ++bb)
        #pragma unroll
        for (int vv = 0; vv < 4; ++vv)
          acc[bb][vv] = fmaf(hvx[bb], wvx[vv], acc[bb][vv]);
    }
    __syncthreads();
  }
  float bias[4];
  #pragma unroll
  for (int vv = 0; vv < 4; ++vv) bias[vv] = lb[vt * 128 + vi + vv];
  float* red = smem;   // [64][32][5]
  #pragma unroll
  for (int bb = 0; bb < 8; ++bb) {
    const int b = bi + bb;
    const int v0 = vt * 128 + vi;
    Part p;
    {
      float lg = acc[bb][0] + bias[0];
      p.bv = lg + gumbel_for(k1t, k2t, (uint32_t)(b * VV + v0));
      p.bix = v0; p.blog = lg; p.m = lg; p.s = 1.0f;
    }
    #pragma unroll
    for (int vv = 1; vv < 4; ++vv) {
      float lg = acc[bb][vv] + bias[vv];
      float pe = lg + gumbel_for(k1t, k2t, (uint32_t)(b * VV + v0 + vv));
      if (pe > p.bv) { p.bv = pe; p.bix = v0 + vv; p.blog = lg; }
      if (lg > p.m) { p.s = p.s * expf(p.m - lg) + 1.f; p.m = lg; }
      else          { p.s += expf(lg - p.m); }
    }
    const int slot = (b * 32 + (tx & 31)) * 5;
    red[slot + 0] = p.bv; red[slot + 1] = __int_as_float(p.bix); red[slot + 2] = p.blog;
    red[slot + 3] = p.m;  red[slot + 4] = p.s;
  }
  __syncthreads();
  if (tx < 64) {
    const int b = tx;
    Part P;
    { const int s0 = (b * 32) * 5;
      P.bv = red[s0]; P.bix = __float_as_int(red[s0 + 1]); P.blog = red[s0 + 2];
      P.m = red[s0 + 3]; P.s = red[s0 + 4]; }
    for (int c = 1; c < 32; ++c) {
      const int s0 = (b * 32 + c) * 5;
      Part Q; Q.bv = red[s0]; Q.bix = __float_as_int(red[s0 + 1]); Q.blog = red[s0 + 2];
      Q.m = red[s0 + 3]; Q.s = red[s0 + 4];
      part_combine(P, Q);
    }
    pf4[vt * BB + b] = make_float4(P.bv, P.blog, P.m, P.s);
    pidx[vt * BB + b] = P.bix;
  }
}

// ---------------- K3: combine partials, sample, record (FLOAT32 out), embed-gather ----------------
__global__ __launch_bounds__(256) void k_sample(const float4* __restrict__ pf4,
                                                const int* __restrict__ pidx,
                                                const float* __restrict__ embW,
                                                int* __restrict__ done,
                                                float* __restrict__ x,
                                                float* __restrict__ out,
                                                int step) {
  const int b = blockIdx.x;
  const int tx = threadIdx.x;
  __shared__ float red[256 * 5];
  __shared__ int stok;
  Part p; p.bv = -FLT_MAX; p.bix = 0x7fffffff; p.blog = 0.f; p.m = -FLT_MAX; p.s = 0.f;
  if (tx < 250) {
    float4 q = pf4[tx * BB + b];
    p.bv = q.x; p.blog = q.y; p.m = q.z; p.s = q.w; p.bix = pidx[tx * BB + b];
  }
  red[tx * 5 + 0] = p.bv; red[tx * 5 + 1] = __int_as_float(p.bix); red[tx * 5 + 2] = p.blog;
  red[tx * 5 + 3] = p.m;  red[tx * 5 + 4] = p.s;
  __syncthreads();
  for (int st = 128; st > 0; st >>= 1) {
    if (tx < st) {
      const int s0 = tx * 5, s1 = (tx + st) * 5;
      Part P, Q;
      P.bv = red[s0]; P.bix = __float_as_int(red[s0 + 1]); P.blog = red[s0 + 2]; P.m = red[s0 + 3]; P.s = red[s0 + 4];
      Q.bv = red[s1]; Q.bix = __float_as_int(red[s1 + 1]); Q.blog = red[s1 + 2]; Q.m = red[s1 + 3]; Q.s = red[s1 + 4];
      part_combine(P, Q);
      red[s0] = P.bv; red[s0 + 1] = __int_as_float(P.bix); red[s0 + 2] = P.blog; red[s0 + 3] = P.m; red[s0 + 4] = P.s;
    }
    __syncthreads();
  }
  if (tx == 0) {
    const int tok = __float_as_int(red[1]);
    const float blog = red[2], M = red[3], S = red[4];
    const float lp = blog - (M + logf(S));
    const int dn = done[b];
    out[b * TT + step] = dn ? 0.0f : (float)tok;              // ids chunk (float32)
    out[BB * TT + b * TT + step] = dn ? 0.0f : lp;            // logps chunk (float32)
    done[b] = dn | (tok == 2);
    stok = tok;
  }
  __syncthreads();
  const int tok = stok;
  for (int e = tx; e < EE; e += 256) x[b * EE + e] = embW[(size_t)tok * EE + e];
}

// ---------------- launch ----------------
extern "C" void kernel_launch(void* const* d_in, const int* in_sizes, int n_in,
                              void* d_out, int out_size, void* d_ws, size_t ws_size,
                              hipStream_t stream) {
  const float* features = (const float*)d_in[0];
  const float* embW     = (const float*)d_in[4];
  const float* Wih      = (const float*)d_in[5];
  const float* Whh      = (const float*)d_in[6];
  const float* bih      = (const float*)d_in[7];
  const float* bhh      = (const float*)d_in[8];
  const float* LW       = (const float*)d_in[9];
  const float* lb       = (const float*)d_in[10];

  float* ws = (float*)d_ws;
  float* hA   = ws;                        // 32768
  float* hB   = ws + 32768;                // 32768
  float* cT   = ws + 65536;                // 32768
  float* x    = ws + 98304;                // 32768
  float4* pf4 = (float4*)(ws + 131072);    // 250*64 float4 (64000 floats), 16B-aligned
  int*   pidx = (int*)(ws + 131072 + 64000);
  int*   done = (int*)(ws + 131072 + 64000 + 16000);
  float* out  = (float*)d_out;             // (int32, float32) tuple -> harness gives float*

  // partitionable (foldlike) split of key(42): key_t = threefry((0,42), (0,t)) full pair
  uint32_t keys[TT][2];
  for (int t = 0; t < TT; ++t) tf2x32(0u, 42u, 0u, (uint32_t)t, keys[t][0], keys[t][1]);

  k_init<<<dim3(128), dim3(256), 0, stream>>>(hA, cT, done);
  const float* hin = hA;
  float* hout = hB;
  for (int t = 0; t < TT; ++t) {
    const float* xin = (t == 0) ? features : x;
    k_cell<<<dim3(64), dim3(256), 0, stream>>>(xin, hin, Wih, Whh, bih, bhh, cT, hout);
    k_logits<<<dim3(250), dim3(256), 0, stream>>>(hout, LW, lb, keys[t][0], keys[t][1], pf4, pidx);
    k_sample<<<dim3(64), dim3(256), 0, stream>>>(pf4, pidx, embW, done, x, out, t);
    const float* tmp = hout; hout = (float*)hin; hin = tmp;
  }
}

// Round 5
// 1847.799 us; speedup vs baseline: 1.3035x; 1.3035x over previous
//
#include <hip/hip_runtime.h>
#include <hip/hip_bf16.h>
#include <stdint.h>
#include <float.h>

// B=64, E=H=512, V=32000, T=20 (lengths[0]=T so max(lengths)==20 always)
#define BB 64
#define EE 512
#define HH 512
#define VV 32000
#define TT 20

// ---------------- threefry2x32 (JAX-exact, 20 rounds) ----------------
__device__ __host__ __forceinline__ void tf2x32(uint32_t k0, uint32_t k1, uint32_t x0, uint32_t x1,
                                                uint32_t& o0, uint32_t& o1) {
  const uint32_t k2 = k0 ^ k1 ^ 0x1BD11BDAu;
  x0 += k0; x1 += k1;
#define RND(R) { x0 += x1; x1 = (x1 << R) | (x1 >> (32 - R)); x1 ^= x0; }
  RND(13) RND(15) RND(26) RND(6)
  x0 += k1; x1 += k2 + 1u;
  RND(17) RND(29) RND(16) RND(24)
  x0 += k2; x1 += k0 + 2u;
  RND(13) RND(15) RND(26) RND(6)
  x0 += k0; x1 += k1 + 3u;
  RND(17) RND(29) RND(16) RND(24)
  x0 += k1; x1 += k2 + 4u;
  RND(13) RND(15) RND(26) RND(6)
  x0 += k2; x1 += k0 + 5u;
#undef RND
  o0 = x0; o1 = x1;
}

// partitionable-threefry (JAX >= 0.5 default): bits = o0^o1 of tf(key,(0,idx));
// uniform = bitcast(0x3f800000|bits>>9)-1, 0 -> tiny; gumbel = -log(-log(u))
__device__ __forceinline__ float gumbel_for(uint32_t k1t, uint32_t k2t, uint32_t idx) {
  uint32_t o0, o1; tf2x32(k1t, k2t, 0u, idx, o0, o1);
  uint32_t bits = o0 ^ o1;
  uint32_t mant = bits >> 9;
  float f = __uint_as_float(0x3f800000u | mant) - 1.0f;
  float u = mant ? f : 1.1754943508222875e-38f;
  return -logf(-logf(u));
}

struct Part { float bv; int bix; float blog; float m; float s; };

__device__ __forceinline__ void part_combine(Part& P, const Part& Q) {
  if (Q.bv > P.bv || (Q.bv == P.bv && Q.bix < P.bix)) { P.bv = Q.bv; P.bix = Q.bix; P.blog = Q.blog; }
  if (Q.m > P.m) { P.s = P.s * expf(P.m - Q.m) + Q.s; P.m = Q.m; }
  else           { P.s += Q.s * expf(Q.m - P.m); }
}

// ---------------- K0: init ----------------
__global__ __launch_bounds__(256) void k_init(float* __restrict__ hA, float* __restrict__ cT,
                                              int* __restrict__ done) {
  int i = blockIdx.x * 256 + threadIdx.x;
  if (i < HH * BB) { hA[i] = 0.f; cT[i] = 0.f; }
  if (i < BB) done[i] = 0;
}

// ============================================================================
// FAST PATH (needs ~6 MB ws)
// ============================================================================

// ---- k_gates: split-k gates GEMM (round-1 proven code) ----
// gatesP[kc][j][b] = sum over k-chunk kc of A[b][k]*W[j][k], A=[x|h], K=1024 in 8 chunks of 128
__global__ __launch_bounds__(256) void k_gates(const float* __restrict__ xin,  // [64][512] b-major
                                               const float* __restrict__ hT,   // [512][64]
                                               const float* __restrict__ Wih,
                                               const float* __restrict__ Whh,
                                               float* __restrict__ gatesP) {
  const int jt = blockIdx.x;   // 0..31  (64 j each)
  const int kc = blockIdx.y;   // 0..7   (128 k each)
  const int tx = threadIdx.x;
  __shared__ float a[64][64];     // [kk][b]
  __shared__ float wj[64][68];    // [kk][j] padded
  const int bi = (tx & 15) * 4;
  const int ji = (tx >> 4) * 4;
  float acc[4][4] = {};
  const float* Wsrc = (kc < 4) ? Wih : Whh;
  for (int s = 0; s < 2; ++s) {
    const int kg = kc * 128 + s * 64;
    if (kc < 4) {
      #pragma unroll
      for (int r = 0; r < 4; ++r) {
        int fi = r * 256 + tx;
        int b = fi >> 4, k4 = (fi & 15) * 4;
        const float4 v = *(const float4*)(xin + b * EE + kg + k4);
        a[k4 + 0][b] = v.x; a[k4 + 1][b] = v.y; a[k4 + 2][b] = v.z; a[k4 + 3][b] = v.w;
      }
    } else {
      #pragma unroll
      for (int r = 0; r < 4; ++r) {
        int fi = r * 256 + tx;
        int row = fi >> 4, c4 = (fi & 15) * 4;
        *(float4*)(&a[row][c4]) = *(const float4*)(hT + (kg - 512 + row) * BB + c4);
      }
    }
    const int kcol = kg & 511;
    #pragma unroll
    for (int r = 0; r < 4; ++r) {
      int fi = r * 256 + tx;
      int j = fi >> 4, k4 = (fi & 15) * 4;
      const float4 v = *(const float4*)(Wsrc + (size_t)(jt * 64 + j) * EE + kcol + k4);
      wj[k4 + 0][j] = v.x; wj[k4 + 1][j] = v.y; wj[k4 + 2][j] = v.z; wj[k4 + 3][j] = v.w;
    }
    __syncthreads();
    #pragma unroll 8
    for (int kk = 0; kk < 64; ++kk) {
      const float4 av = *(const float4*)(&a[kk][bi]);
      const float4 wv = *(const float4*)(&wj[kk][ji]);
      const float avx[4] = {av.x, av.y, av.z, av.w};
      const float wvx[4] = {wv.x, wv.y, wv.z, wv.w};
      #pragma unroll
      for (int jj = 0; jj < 4; ++jj)
        #pragma unroll
        for (int bb = 0; bb < 4; ++bb)
          acc[jj][bb] = fmaf(wvx[jj], avx[bb], acc[jj][bb]);
    }
    __syncthreads();
  }
  #pragma unroll
  for (int jj = 0; jj < 4; ++jj) {
    float4 o = make_float4(acc[jj][0], acc[jj][1], acc[jj][2], acc[jj][3]);
    *(float4*)(gatesP + ((size_t)kc * 2048 + jt * 64 + ji + jj) * BB + bi) = o;
  }
}

// ---- k_lstm_update: sum partials + activations + h,c update (round-1 proven) ----
__global__ __launch_bounds__(256) void k_lstm_update(const float* __restrict__ gatesP,
                                                     const float* __restrict__ b_ih,
                                                     const float* __restrict__ b_hh,
                                                     float* __restrict__ cT,
                                                     float* __restrict__ hT) {
  const int blk = blockIdx.x;
  const int tx = threadIdx.x;
  const int b = tx & 63;
  const int dk = tx >> 6;
  #pragma unroll
  for (int r = 0; r < 2; ++r) {
    const int k = blk * 8 + dk + r * 4;
    float g[4];
    #pragma unroll
    for (int gi = 0; gi < 4; ++gi) {
      const int j = gi * 512 + k;
      float s = 0.f;
      #pragma unroll
      for (int kc = 0; kc < 8; ++kc) s += gatesP[((size_t)kc * 2048 + j) * BB + b];
      g[gi] = s + b_ih[j] + b_hh[j];
    }
    const float ig = 1.f / (1.f + expf(-g[0]));
    const float fg = 1.f / (1.f + expf(-g[1]));
    const float gg = tanhf(g[2]);
    const float og = 1.f / (1.f + expf(-g[3]));
    const float c = fg * cT[k * BB + b] + ig * gg;
    cT[k * BB + b] = c;
    hT[k * BB + b] = og * tanhf(c);
  }
}

// ---- k_logits2: 1000 blocks x 128 thr; 32v x 64b tile; W in swizzled LDS, h from global ----
// Per-thread 2v x 8b. K summation order = 8 chunks of 64 sequential (bit-identical to r4).
__global__ __launch_bounds__(128) void k_logits2(const float* __restrict__ hT,
                                                 const float* __restrict__ LW,
                                                 const float* __restrict__ lb,
                                                 uint32_t k1t, uint32_t k2t,
                                                 float4* __restrict__ pf4,
                                                 int* __restrict__ pidx) {
  const int vt = blockIdx.x;        // 0..999 (32 v each)
  const int tx = threadIdx.x;       // 0..127
  __shared__ float lds[5120];       // union: wTs[64*32]=2048 f | red[64][16][5]=5120 f
  float* wTs = lds;
  const int vthr = tx & 15;         // 16 v-pair groups
  const int bthr = tx >> 4;         // 8 b-octet groups
  const int vi = vthr * 2;          // logical v offset in tile (0..30)
  const int bi = bthr * 8;          // b offset (0..56)
  const int vq = tx >> 4;           // staging: v-quad 0..7 (4 v each = 32)
  const int ks = tx & 15;           // staging: kk base
  float acc[2][8] = {};             // [v][b]

  for (int kt = 0; kt < 8; ++kt) {
    const int kg = kt * 64;
    // stage W chunk [32 v][64 k] -> wTs[kk][v ^ 4*(kk&7)] via register transpose, b128 stores
    #pragma unroll
    for (int s = 0; s < 4; ++s) {
      const int kk = ks + 16 * s;
      const size_t rb = (size_t)(vt * 32 + 4 * vq) * HH + kg + kk;
      float w0 = LW[rb];
      float w1 = LW[rb + HH];
      float w2 = LW[rb + 2 * HH];
      float w3 = LW[rb + 3 * HH];
      const int ph = (4 * vq) ^ (4 * (kk & 7));
      *(float4*)&wTs[kk * 32 + ph] = make_float4(w0, w1, w2, w3);
    }
    __syncthreads();
    #pragma unroll 4
    for (int kk = 0; kk < 64; ++kk) {
      const float* hrow = hT + (size_t)(kg + kk) * BB;
      const float4 h0 = *(const float4*)(hrow + bi);
      const float4 h1 = *(const float4*)(hrow + bi + 4);
      const float2 wv = *(const float2*)&wTs[kk * 32 + (vi ^ (4 * (kk & 7)))];
      acc[0][0] = fmaf(wv.x, h0.x, acc[0][0]); acc[0][1] = fmaf(wv.x, h0.y, acc[0][1]);
      acc[0][2] = fmaf(wv.x, h0.z, acc[0][2]); acc[0][3] = fmaf(wv.x, h0.w, acc[0][3]);
      acc[0][4] = fmaf(wv.x, h1.x, acc[0][4]); acc[0][5] = fmaf(wv.x, h1.y, acc[0][5]);
      acc[0][6] = fmaf(wv.x, h1.z, acc[0][6]); acc[0][7] = fmaf(wv.x, h1.w, acc[0][7]);
      acc[1][0] = fmaf(wv.y, h0.x, acc[1][0]); acc[1][1] = fmaf(wv.y, h0.y, acc[1][1]);
      acc[1][2] = fmaf(wv.y, h0.z, acc[1][2]); acc[1][3] = fmaf(wv.y, h0.w, acc[1][3]);
      acc[1][4] = fmaf(wv.y, h1.x, acc[1][4]); acc[1][5] = fmaf(wv.y, h1.y, acc[1][5]);
      acc[1][6] = fmaf(wv.y, h1.z, acc[1][6]); acc[1][7] = fmaf(wv.y, h1.w, acc[1][7]);
    }
    __syncthreads();
  }

  // epilogue: bias + gumbel + per-b Part over this thread's 2 v's
  const int v0g = vt * 32 + vi;
  const float bias0 = lb[v0g];
  const float bias1 = lb[v0g + 1];
  float* red = lds;                 // [64][16][5]
  #pragma unroll
  for (int bb = 0; bb < 8; ++bb) {
    const int b = bi + bb;
    const float lg0 = acc[0][bb] + bias0;
    const float lg1 = acc[1][bb] + bias1;
    Part p;
    p.bv = lg0 + gumbel_for(k1t, k2t, (uint32_t)(b * VV + v0g));
    p.bix = v0g; p.blog = lg0;
    const float pe1 = lg1 + gumbel_for(k1t, k2t, (uint32_t)(b * VV + v0g + 1));
    if (pe1 > p.bv) { p.bv = pe1; p.bix = v0g + 1; p.blog = lg1; }
    if (lg0 >= lg1) { p.m = lg0; p.s = 1.f + expf(lg1 - lg0); }
    else            { p.m = lg1; p.s = 1.f + expf(lg0 - lg1); }
    const int slot = (b * 16 + vthr) * 5;
    red[slot + 0] = p.bv; red[slot + 1] = __int_as_float(p.bix); red[slot + 2] = p.blog;
    red[slot + 3] = p.m;  red[slot + 4] = p.s;
  }
  __syncthreads();
  if (tx < 64) {
    const int b = tx;
    Part P;
    { const int s0 = (b * 16) * 5;
      P.bv = red[s0]; P.bix = __float_as_int(red[s0 + 1]); P.blog = red[s0 + 2];
      P.m = red[s0 + 3]; P.s = red[s0 + 4]; }
    #pragma unroll
    for (int c = 1; c < 16; ++c) {
      const int s0 = (b * 16 + c) * 5;
      Part Q; Q.bv = red[s0]; Q.bix = __float_as_int(red[s0 + 1]); Q.blog = red[s0 + 2];
      Q.m = red[s0 + 3]; Q.s = red[s0 + 4];
      part_combine(P, Q);
    }
    pf4[(size_t)vt * BB + b] = make_float4(P.bv, P.blog, P.m, P.s);
    pidx[vt * BB + b] = P.bix;
  }
}

// ---- k_sample2: combine 1000 partials, sample, record, embed-gather ----
__global__ __launch_bounds__(256) void k_sample2(const float4* __restrict__ pf4,
                                                 const int* __restrict__ pidx,
                                                 const float* __restrict__ embW,
                                                 int* __restrict__ done,
                                                 float* __restrict__ x,
                                                 float* __restrict__ out,
                                                 int step) {
  const int b = blockIdx.x;
  const int tx = threadIdx.x;
  __shared__ float red[256 * 5];
  __shared__ int stok;
  Part p; p.bv = -FLT_MAX; p.bix = 0x7fffffff; p.blog = 0.f; p.m = -FLT_MAX; p.s = 0.f;
  #pragma unroll
  for (int i = 0; i < 4; ++i) {
    const int vt = tx + 256 * i;
    if (vt < 1000) {
      float4 q = pf4[(size_t)vt * BB + b];
      Part Q; Q.bv = q.x; Q.blog = q.y; Q.m = q.z; Q.s = q.w; Q.bix = pidx[vt * BB + b];
      part_combine(p, Q);
    }
  }
  red[tx * 5 + 0] = p.bv; red[tx * 5 + 1] = __int_as_float(p.bix); red[tx * 5 + 2] = p.blog;
  red[tx * 5 + 3] = p.m;  red[tx * 5 + 4] = p.s;
  __syncthreads();
  for (int st = 128; st > 0; st >>= 1) {
    if (tx < st) {
      const int s0 = tx * 5, s1 = (tx + st) * 5;
      Part P, Q;
      P.bv = red[s0]; P.bix = __float_as_int(red[s0 + 1]); P.blog = red[s0 + 2]; P.m = red[s0 + 3]; P.s = red[s0 + 4];
      Q.bv = red[s1]; Q.bix = __float_as_int(red[s1 + 1]); Q.blog = red[s1 + 2]; Q.m = red[s1 + 3]; Q.s = red[s1 + 4];
      part_combine(P, Q);
      red[s0] = P.bv; red[s0 + 1] = __int_as_float(P.bix); red[s0 + 2] = P.blog; red[s0 + 3] = P.m; red[s0 + 4] = P.s;
    }
    __syncthreads();
  }
  if (tx == 0) {
    const int tok = __float_as_int(red[1]);
    const float blog = red[2], M = red[3], S = red[4];
    const float lp = blog - (M + logf(S));
    const int dn = done[b];
    out[b * TT + step] = dn ? 0.0f : (float)tok;
    out[BB * TT + b * TT + step] = dn ? 0.0f : lp;
    done[b] = dn | (tok == 2);
    stok = tok;
  }
  __syncthreads();
  const int tok = stok;
  for (int e = tx; e < EE; e += 256) x[b * EE + e] = embW[(size_t)tok * EE + e];
}

// ============================================================================
// FALLBACK PATH (round-4 verbatim, ~845 KB ws) — used if ws_size < 6.25 MB
// ============================================================================

__global__ __launch_bounds__(256) void k_cell(const float* __restrict__ xin,
                                              const float* __restrict__ hin,
                                              const float* __restrict__ Wih,
                                              const float* __restrict__ Whh,
                                              const float* __restrict__ bih,
                                              const float* __restrict__ bhh,
                                              float* __restrict__ cT,
                                              float* __restrict__ hout) {
  const int jt = blockIdx.x;
  const int tx = threadIdx.x;
  __shared__ float a[64][64];
  __shared__ float wj[64][34];
  const int b0 = (tx & 15) * 4;
  const int r0 = (tx >> 4) * 2;
  float acc[2][4] = {};
  for (int kc = 0; kc < 16; ++kc) {
    const int kg = kc * 64;
    if (kg < 512) {
      #pragma unroll
      for (int r = 0; r < 4; ++r) {
        int fi = r * 256 + tx;
        int b = fi >> 4, k4 = (fi & 15) * 4;
        const float4 v = *(const float4*)(xin + b * EE + kg + k4);
        a[k4 + 0][b] = v.x; a[k4 + 1][b] = v.y; a[k4 + 2][b] = v.z; a[k4 + 3][b] = v.w;
      }
    } else {
      #pragma unroll
      for (int r = 0; r < 4; ++r) {
        int fi = r * 256 + tx;
        int kk = fi >> 4, b4 = (fi & 15) * 4;
        *(float4*)(&a[kk][b4]) = *(const float4*)(hin + (kg - 512 + kk) * BB + b4);
      }
    }
    {
      const float* Wsrc = (kg < 512) ? Wih : Whh;
      const int kcol = kg & 511;
      #pragma unroll
      for (int r = 0; r < 2; ++r) {
        int fi = r * 256 + tx;
        int slot = fi >> 4, k4 = (fi & 15) * 4;
        int g = slot >> 3, q = slot & 7;
        const float4 v = *(const float4*)(Wsrc + (size_t)(g * 512 + jt * 8 + q) * 512 + kcol + k4);
        wj[k4 + 0][slot] = v.x; wj[k4 + 1][slot] = v.y;
        wj[k4 + 2][slot] = v.z; wj[k4 + 3][slot] = v.w;
      }
    }
    __syncthreads();
    #pragma unroll 8
    for (int kk = 0; kk < 64; ++kk) {
      const float4 av = *(const float4*)(&a[kk][b0]);
      const float w0 = wj[kk][r0], w1 = wj[kk][r0 + 1];
      acc[0][0] = fmaf(w0, av.x, acc[0][0]); acc[0][1] = fmaf(w0, av.y, acc[0][1]);
      acc[0][2] = fmaf(w0, av.z, acc[0][2]); acc[0][3] = fmaf(w0, av.w, acc[0][3]);
      acc[1][0] = fmaf(w1, av.x, acc[1][0]); acc[1][1] = fmaf(w1, av.y, acc[1][1]);
      acc[1][2] = fmaf(w1, av.z, acc[1][2]); acc[1][3] = fmaf(w1, av.w, acc[1][3]);
    }
    __syncthreads();
  }
  float* gl = &a[0][0];
  *(float4*)(gl + (r0 + 0) * 64 + b0) = make_float4(acc[0][0], acc[0][1], acc[0][2], acc[0][3]);
  *(float4*)(gl + (r0 + 1) * 64 + b0) = make_float4(acc[1][0], acc[1][1], acc[1][2], acc[1][3]);
  __syncthreads();
  #pragma unroll
  for (int r = 0; r < 2; ++r) {
    const int idx = r * 256 + tx;
    const int q = idx >> 6, b = idx & 63;
    const int jb = jt * 8 + q;
    const float gi = gl[(0 * 8 + q) * 64 + b] + bih[jb]        + bhh[jb];
    const float gf = gl[(1 * 8 + q) * 64 + b] + bih[512 + jb]  + bhh[512 + jb];
    const float gg = gl[(2 * 8 + q) * 64 + b] + bih[1024 + jb] + bhh[1024 + jb];
    const float go = gl[(3 * 8 + q) * 64 + b] + bih[1536 + jb] + bhh[1536 + jb];
    const float ig = 1.f / (1.f + expf(-gi));
    const float fg = 1.f / (1.f + expf(-gf));
    const float g  = tanhf(gg);
    const float og = 1.f / (1.f + expf(-go));
    const float c = fg * cT[jb * BB + b] + ig * g;
    cT[jb * BB + b] = c;
    hout[jb * BB + b] = og * tanhf(c);
  }
}

__global__ __launch_bounds__(256) void k_logits_v1(const float* __restrict__ hT,
                                                   const float* __restrict__ LW,
                                                   const float* __restrict__ lb,
                                                   uint32_t k1t, uint32_t k2t,
                                                   float4* __restrict__ pf4,
                                                   int* __restrict__ pidx) {
  const int vt = blockIdx.x;
  const int tx = threadIdx.x;
  __shared__ float smem[4096 + 64 * 132];
  float* hs = smem;
  float* wT = smem + 4096;
  const int vi = (tx & 31) * 4;
  const int bi = (tx >> 5) * 8;
  float acc[8][4] = {};
  for (int kt = 0; kt < 8; ++kt) {
    #pragma unroll
    for (int r = 0; r < 4; ++r) {
      int fi = r * 256 + tx;
      int row = fi >> 4, c4 = (fi & 15) * 4;
      *(float4*)(hs + (row << 6) + c4) = *(const float4*)(hT + (kt * 64 + row) * BB + c4);
    }
    #pragma unroll
    for (int r = 0; r < 8; ++r) {
      int fi = r * 256 + tx;
      int v = fi >> 4, k4 = (fi & 15) * 4;
      const float4 w = *(const float4*)(LW + (size_t)(vt * 128 + v) * HH + kt * 64 + k4);
      wT[(k4 + 0) * 132 + v] = w.x; wT[(k4 + 1) * 132 + v] = w.y;
      wT[(k4 + 2) * 132 + v] = w.z; wT[(k4 + 3) * 132 + v] = w.w;
    }
    __syncthreads();
    #pragma unroll 4
    for (int kk = 0; kk < 64; ++kk) {
      const float4 w4 = *(const float4*)(wT + kk * 132 + vi);
      const float4 h0 = *(const float4*)(hs + (kk << 6) + bi);
      const float4 h1 = *(const float4*)(hs + (kk << 6) + bi + 4);
      const float wvx[4] = {w4.x, w4.y, w4.z, w4.w};
      const float hvx[8] = {h0.x, h0.y, h0.z, h0.w, h1.x, h1.y, h1.z, h1.w};
      #pragma unroll
      for (int bb = 0; bb < 8; ++bb)
        #pragma unroll
        for (int vv = 0; vv < 4; ++vv)
          acc[bb][vv] = fmaf(hvx[bb], wvx[vv], acc[bb][vv]);
    }
    __syncthreads();
  }
  float bias[4];
  #pragma unroll
  for (int vv = 0; vv < 4; ++vv) bias[vv] = lb[vt * 128 + vi + vv];
  float* red = smem;
  #pragma unroll
  for (int bb = 0; bb < 8; ++bb) {
    const int b = bi + bb;
    const int v0 = vt * 128 + vi;
    Part p;
    {
      float lg = acc[bb][0] + bias[0];
      p.bv = lg + gumbel_for(k1t, k2t, (uint32_t)(b * VV + v0));
      p.bix = v0; p.blog = lg; p.m = lg; p.s = 1.0f;
    }
    #pragma unroll
    for (int vv = 1; vv < 4; ++vv) {
      float lg = acc[bb][vv] + bias[vv];
      float pe = lg + gumbel_for(k1t, k2t, (uint32_t)(b * VV + v0 + vv));
      if (pe > p.bv) { p.bv = pe; p.bix = v0 + vv; p.blog = lg; }
      if (lg > p.m) { p.s = p.s * expf(p.m - lg) + 1.f; p.m = lg; }
      else          { p.s += expf(lg - p.m); }
    }
    const int slot = (b * 32 + (tx & 31)) * 5;
    red[slot + 0] = p.bv; red[slot + 1] = __int_as_float(p.bix); red[slot + 2] = p.blog;
    red[slot + 3] = p.m;  red[slot + 4] = p.s;
  }
  __syncthreads();
  if (tx < 64) {
    const int b = tx;
    Part P;
    { const int s0 = (b * 32) * 5;
      P.bv = red[s0]; P.bix = __float_as_int(red[s0 + 1]); P.blog = red[s0 + 2];
      P.m = red[s0 + 3]; P.s = red[s0 + 4]; }
    for (int c = 1; c < 32; ++c) {
      const int s0 = (b * 32 + c) * 5;
      Part Q; Q.bv = red[s0]; Q.bix = __float_as_int(red[s0 + 1]); Q.blog = red[s0 + 2];
      Q.m = red[s0 + 3]; Q.s = red[s0 + 4];
      part_combine(P, Q);
    }
    pf4[vt * BB + b] = make_float4(P.bv, P.blog, P.m, P.s);
    pidx[vt * BB + b] = P.bix;
  }
}

__global__ __launch_bounds__(256) void k_sample_v1(const float4* __restrict__ pf4,
                                                   const int* __restrict__ pidx,
                                                   const float* __restrict__ embW,
                                                   int* __restrict__ done,
                                                   float* __restrict__ x,
                                                   float* __restrict__ out,
                                                   int step) {
  const int b = blockIdx.x;
  const int tx = threadIdx.x;
  __shared__ float red[256 * 5];
  __shared__ int stok;
  Part p; p.bv = -FLT_MAX; p.bix = 0x7fffffff; p.blog = 0.f; p.m = -FLT_MAX; p.s = 0.f;
  if (tx < 250) {
    float4 q = pf4[tx * BB + b];
    p.bv = q.x; p.blog = q.y; p.m = q.z; p.s = q.w; p.bix = pidx[tx * BB + b];
  }
  red[tx * 5 + 0] = p.bv; red[tx * 5 + 1] = __int_as_float(p.bix); red[tx * 5 + 2] = p.blog;
  red[tx * 5 + 3] = p.m;  red[tx * 5 + 4] = p.s;
  __syncthreads();
  for (int st = 128; st > 0; st >>= 1) {
    if (tx < st) {
      const int s0 = tx * 5, s1 = (tx + st) * 5;
      Part P, Q;
      P.bv = red[s0]; P.bix = __float_as_int(red[s0 + 1]); P.blog = red[s0 + 2]; P.m = red[s0 + 3]; P.s = red[s0 + 4];
      Q.bv = red[s1]; Q.bix = __float_as_int(red[s1 + 1]); Q.blog = red[s1 + 2]; Q.m = red[s1 + 3]; Q.s = red[s1 + 4];
      part_combine(P, Q);
      red[s0] = P.bv; red[s0 + 1] = __int_as_float(P.bix); red[s0 + 2] = P.blog; red[s0 + 3] = P.m; red[s0 + 4] = P.s;
    }
    __syncthreads();
  }
  if (tx == 0) {
    const int tok = __float_as_int(red[1]);
    const float blog = red[2], M = red[3], S = red[4];
    const float lp = blog - (M + logf(S));
    const int dn = done[b];
    out[b * TT + step] = dn ? 0.0f : (float)tok;
    out[BB * TT + b * TT + step] = dn ? 0.0f : lp;
    done[b] = dn | (tok == 2);
    stok = tok;
  }
  __syncthreads();
  const int tok = stok;
  for (int e = tx; e < EE; e += 256) x[b * EE + e] = embW[(size_t)tok * EE + e];
}

// ---------------- launch ----------------
extern "C" void kernel_launch(void* const* d_in, const int* in_sizes, int n_in,
                              void* d_out, int out_size, void* d_ws, size_t ws_size,
                              hipStream_t stream) {
  const float* features = (const float*)d_in[0];
  const float* embW     = (const float*)d_in[4];
  const float* Wih      = (const float*)d_in[5];
  const float* Whh      = (const float*)d_in[6];
  const float* bih      = (const float*)d_in[7];
  const float* bhh      = (const float*)d_in[8];
  const float* LW       = (const float*)d_in[9];
  const float* lb       = (const float*)d_in[10];
  float* out = (float*)d_out;

  // step keys: partitionable (foldlike) split of key(42)
  uint32_t keys[TT][2];
  for (int t = 0; t < TT; ++t) tf2x32(0u, 42u, 0u, (uint32_t)t, keys[t][0], keys[t][1]);

  float* ws = (float*)d_ws;
  float* hA   = ws;                        // 32768
  float* hB   = ws + 32768;
  float* cT   = ws + 65536;
  float* x    = ws + 98304;

  if (ws_size >= (size_t)(6400u * 1024u)) {
    // fast path: gatesP 4MB + pf4 1000x64 + pidx
    float* gatesP = ws + 131072;                       // 8*2048*64 = 1,048,576 f
    float4* pf4   = (float4*)(ws + 131072 + 1048576);  // 1000*64*4 f = 256,000 f
    int*   pidx   = (int*)(ws + 131072 + 1048576 + 256000);  // 64,000
    int*   done   = (int*)(ws + 131072 + 1048576 + 256000 + 64000);

    k_init<<<dim3(128), dim3(256), 0, stream>>>(hA, cT, done);
    const float* hin = hA;
    float* hout = hB;
    for (int t = 0; t < TT; ++t) {
      const float* xin = (t == 0) ? features : x;
      k_gates<<<dim3(32, 8), dim3(256), 0, stream>>>(xin, hin, Wih, Whh, gatesP);
      k_lstm_update<<<dim3(64), dim3(256), 0, stream>>>(gatesP, bih, bhh, cT, hout);
      k_logits2<<<dim3(1000), dim3(128), 0, stream>>>(hout, LW, lb, keys[t][0], keys[t][1], pf4, pidx);
      k_sample2<<<dim3(64), dim3(256), 0, stream>>>(pf4, pidx, embW, done, x, out, t);
      const float* tmp = hout; hout = (float*)hin; hin = tmp;
    }
  } else {
    // fallback: round-4 kernels (~845 KB ws)
    float4* pf4 = (float4*)(ws + 131072);
    int*   pidx = (int*)(ws + 131072 + 64000);
    int*   done = (int*)(ws + 131072 + 64000 + 16000);

    k_init<<<dim3(128), dim3(256), 0, stream>>>(hA, cT, done);
    const float* hin = hA;
    float* hout = hB;
    for (int t = 0; t < TT; ++t) {
      const float* xin = (t == 0) ? features : x;
      k_cell<<<dim3(64), dim3(256), 0, stream>>>(xin, hin, Wih, Whh, bih, bhh, cT, hout);
      k_logits_v1<<<dim3(250), dim3(256), 0, stream>>>(hout, LW, lb, keys[t][0], keys[t][1], pf4, pidx);
      k_sample_v1<<<dim3(64), dim3(256), 0, stream>>>(pf4, pidx, embW, done, x, out, t);
      const float* tmp = hout; hout = (float*)hin; hin = tmp;
    }
  }
}

// Round 6
// 1111.564 us; speedup vs baseline: 2.1669x; 1.6623x over previous
//
#include <hip/hip_runtime.h>
#include <hip/hip_bf16.h>
#include <stdint.h>
#include <float.h>

// B=64, E=H=512, V=32000, T=20 (lengths[0]=T so max(lengths)==20 always)
#define BB 64
#define EE 512
#define HH 512
#define VV 32000
#define TT 20
#define INV2048 0.00048828125f

typedef _Float16 f16x8 __attribute__((ext_vector_type(8)));
typedef float f32x4 __attribute__((ext_vector_type(4)));

// ---------------- threefry2x32 (JAX-exact, 20 rounds) ----------------
__device__ __host__ __forceinline__ void tf2x32(uint32_t k0, uint32_t k1, uint32_t x0, uint32_t x1,
                                                uint32_t& o0, uint32_t& o1) {
  const uint32_t k2 = k0 ^ k1 ^ 0x1BD11BDAu;
  x0 += k0; x1 += k1;
#define RND(R) { x0 += x1; x1 = (x1 << R) | (x1 >> (32 - R)); x1 ^= x0; }
  RND(13) RND(15) RND(26) RND(6)
  x0 += k1; x1 += k2 + 1u;
  RND(17) RND(29) RND(16) RND(24)
  x0 += k2; x1 += k0 + 2u;
  RND(13) RND(15) RND(26) RND(6)
  x0 += k0; x1 += k1 + 3u;
  RND(17) RND(29) RND(16) RND(24)
  x0 += k1; x1 += k2 + 4u;
  RND(13) RND(15) RND(26) RND(6)
  x0 += k2; x1 += k0 + 5u;
#undef RND
  o0 = x0; o1 = x1;
}

// partitionable-threefry (JAX >= 0.5 default): bits = o0^o1 of tf(key,(0,idx));
// uniform = bitcast(0x3f800000|bits>>9)-1, 0 -> tiny; gumbel = -log(-log(u))
__device__ __forceinline__ float gumbel_for(uint32_t k1t, uint32_t k2t, uint32_t idx) {
  uint32_t o0, o1; tf2x32(k1t, k2t, 0u, idx, o0, o1);
  uint32_t bits = o0 ^ o1;
  uint32_t mant = bits >> 9;
  float f = __uint_as_float(0x3f800000u | mant) - 1.0f;
  float u = mant ? f : 1.1754943508222875e-38f;
  return -logf(-logf(u));
}

struct Part { float bv; int bix; float blog; float m; float s; };

__device__ __forceinline__ void part_combine(Part& P, const Part& Q) {
  if (Q.bv > P.bv || (Q.bv == P.bv && Q.bix < P.bix)) { P.bv = Q.bv; P.bix = Q.bix; P.blog = Q.blog; }
  if (Q.m > P.m) { P.s = P.s * expf(P.m - Q.m) + Q.s; P.m = Q.m; }
  else           { P.s += Q.s * expf(Q.m - P.m); }
}

// ---------------- K0: init ----------------
__global__ __launch_bounds__(256) void k_init(float* __restrict__ hA, float* __restrict__ cT,
                                              int* __restrict__ done) {
  int i = blockIdx.x * 256 + threadIdx.x;
  if (i < HH * BB) { hA[i] = 0.f; cT[i] = 0.f; }
  if (i < BB) done[i] = 0;
}

// ---------------- k_gates: split-k gates GEMM (proven) ----------------
__global__ __launch_bounds__(256) void k_gates(const float* __restrict__ xin,  // [64][512] b-major
                                               const float* __restrict__ hT,   // [512][64]
                                               const float* __restrict__ Wih,
                                               const float* __restrict__ Whh,
                                               float* __restrict__ gatesP) {
  const int jt = blockIdx.x;   // 0..31
  const int kc = blockIdx.y;   // 0..7
  const int tx = threadIdx.x;
  __shared__ float a[64][64];
  __shared__ float wj[64][68];
  const int bi = (tx & 15) * 4;
  const int ji = (tx >> 4) * 4;
  float acc[4][4] = {};
  const float* Wsrc = (kc < 4) ? Wih : Whh;
  for (int s = 0; s < 2; ++s) {
    const int kg = kc * 128 + s * 64;
    if (kc < 4) {
      #pragma unroll
      for (int r = 0; r < 4; ++r) {
        int fi = r * 256 + tx;
        int b = fi >> 4, k4 = (fi & 15) * 4;
        const float4 v = *(const float4*)(xin + b * EE + kg + k4);
        a[k4 + 0][b] = v.x; a[k4 + 1][b] = v.y; a[k4 + 2][b] = v.z; a[k4 + 3][b] = v.w;
      }
    } else {
      #pragma unroll
      for (int r = 0; r < 4; ++r) {
        int fi = r * 256 + tx;
        int row = fi >> 4, c4 = (fi & 15) * 4;
        *(float4*)(&a[row][c4]) = *(const float4*)(hT + (kg - 512 + row) * BB + c4);
      }
    }
    const int kcol = kg & 511;
    #pragma unroll
    for (int r = 0; r < 4; ++r) {
      int fi = r * 256 + tx;
      int j = fi >> 4, k4 = (fi & 15) * 4;
      const float4 v = *(const float4*)(Wsrc + (size_t)(jt * 64 + j) * EE + kcol + k4);
      wj[k4 + 0][j] = v.x; wj[k4 + 1][j] = v.y; wj[k4 + 2][j] = v.z; wj[k4 + 3][j] = v.w;
    }
    __syncthreads();
    #pragma unroll 8
    for (int kk = 0; kk < 64; ++kk) {
      const float4 av = *(const float4*)(&a[kk][bi]);
      const float4 wv = *(const float4*)(&wj[kk][ji]);
      const float avx[4] = {av.x, av.y, av.z, av.w};
      const float wvx[4] = {wv.x, wv.y, wv.z, wv.w};
      #pragma unroll
      for (int jj = 0; jj < 4; ++jj)
        #pragma unroll
        for (int bb = 0; bb < 4; ++bb)
          acc[jj][bb] = fmaf(wvx[jj], avx[bb], acc[jj][bb]);
    }
    __syncthreads();
  }
  #pragma unroll
  for (int jj = 0; jj < 4; ++jj) {
    float4 o = make_float4(acc[jj][0], acc[jj][1], acc[jj][2], acc[jj][3]);
    *(float4*)(gatesP + ((size_t)kc * 2048 + jt * 64 + ji + jj) * BB + bi) = o;
  }
}

// ---------------- k_lstm_update (mid path, no frag writes) ----------------
__global__ __launch_bounds__(256) void k_lstm_update(const float* __restrict__ gatesP,
                                                     const float* __restrict__ b_ih,
                                                     const float* __restrict__ b_hh,
                                                     float* __restrict__ cT,
                                                     float* __restrict__ hT) {
  const int blk = blockIdx.x;
  const int tx = threadIdx.x;
  const int b = tx & 63;
  const int dk = tx >> 6;
  #pragma unroll
  for (int r = 0; r < 2; ++r) {
    const int k = blk * 8 + dk + r * 4;
    float g[4];
    #pragma unroll
    for (int gi = 0; gi < 4; ++gi) {
      const int j = gi * 512 + k;
      float s = 0.f;
      #pragma unroll
      for (int kc = 0; kc < 8; ++kc) s += gatesP[((size_t)kc * 2048 + j) * BB + b];
      g[gi] = s + b_ih[j] + b_hh[j];
    }
    const float ig = 1.f / (1.f + expf(-g[0]));
    const float fg = 1.f / (1.f + expf(-g[1]));
    const float gg = tanhf(g[2]);
    const float og = 1.f / (1.f + expf(-g[3]));
    const float c = fg * cT[k * BB + b] + ig * gg;
    cT[k * BB + b] = c;
    hT[k * BB + b] = og * tanhf(c);
  }
}

// ---------------- k_lstm_update_frag: + fp16 hi/lo B-fragment writes ----------------
// B-frag layout: n=lane&15 (b%16), k = c*32 + (lane>>4)*8 + j; idx = ((c*4+nb)*64+lane)*8+j
__global__ __launch_bounds__(256) void k_lstm_update_frag(const float* __restrict__ gatesP,
                                                          const float* __restrict__ b_ih,
                                                          const float* __restrict__ b_hh,
                                                          float* __restrict__ cT,
                                                          float* __restrict__ hT,
                                                          _Float16* __restrict__ hfh,
                                                          _Float16* __restrict__ hfl) {
  const int blk = blockIdx.x;
  const int tx = threadIdx.x;
  const int b = tx & 63;
  const int dk = tx >> 6;
  #pragma unroll
  for (int r = 0; r < 2; ++r) {
    const int k = blk * 8 + dk + r * 4;
    float g[4];
    #pragma unroll
    for (int gi = 0; gi < 4; ++gi) {
      const int j = gi * 512 + k;
      float s = 0.f;
      #pragma unroll
      for (int kc = 0; kc < 8; ++kc) s += gatesP[((size_t)kc * 2048 + j) * BB + b];
      g[gi] = s + b_ih[j] + b_hh[j];
    }
    const float ig = 1.f / (1.f + expf(-g[0]));
    const float fg = 1.f / (1.f + expf(-g[1]));
    const float gg = tanhf(g[2]);
    const float og = 1.f / (1.f + expf(-g[3]));
    const float c = fg * cT[k * BB + b] + ig * gg;
    cT[k * BB + b] = c;
    const float h = og * tanhf(c);
    hT[k * BB + b] = h;
    const _Float16 hh = (_Float16)h;
    const _Float16 hl = (_Float16)((h - (float)hh) * 2048.0f);
    const int cc = k >> 5, kr = k & 31;
    const int lane = (kr >> 3) * 16 + (b & 15), j = kr & 7, nb = b >> 4;
    const int idx = ((cc * 4 + nb) * 64 + lane) * 8 + j;
    hfh[idx] = hh; hfl[idx] = hl;
  }
}

// ---------------- k_convW: f32 W -> fp16 hi/lo in MFMA A-fragment layout ----------------
// A-frag: m=lane&15 (v%16), k = c*32 + (lane>>4)*8 + j; Wf[((vb*16 + c)*64 + lane)*8 + j]
__global__ __launch_bounds__(256) void k_convW(const float* __restrict__ LW,
                                               _Float16* __restrict__ Wh,
                                               _Float16* __restrict__ Wl) {
  const int t = blockIdx.x * 256 + threadIdx.x;   // 0 .. 32000*64-1
  const int v = t >> 6, kq = t & 63;
  const float4 f0 = *(const float4*)(LW + (size_t)v * HH + kq * 8);
  const float4 f1 = *(const float4*)(LW + (size_t)v * HH + kq * 8 + 4);
  const int vb = v >> 4, m = v & 15;
  const int c = kq >> 2, lh = kq & 3;
  const size_t o = (((size_t)vb * 16 + c) * 64 + lh * 16 + m) * 8;
  const float f[8] = {f0.x, f0.y, f0.z, f0.w, f1.x, f1.y, f1.z, f1.w};
  f16x8 hi, lo;
  #pragma unroll
  for (int j = 0; j < 8; ++j) {
    const _Float16 h = (_Float16)f[j];
    hi[j] = h;
    lo[j] = (_Float16)((f[j] - (float)h) * 2048.0f);
  }
  *(f16x8*)(Wh + o) = hi;
  *(f16x8*)(Wl + o) = lo;
}

// ---------------- k_logits3: MFMA fp16-split logits + gumbel + partials ----------------
// 2000 blocks x 64 thr (1 wave). Block vt: v in [vt*16, vt*16+16), all 64 b, K=512.
__global__ __launch_bounds__(64) void k_logits3(const f16x8* __restrict__ Wh,
                                                const f16x8* __restrict__ Wl,
                                                const f16x8* __restrict__ hfh,
                                                const f16x8* __restrict__ hfl,
                                                const float* __restrict__ lb,
                                                uint32_t k1t, uint32_t k2t,
                                                float4* __restrict__ pf4,
                                                int* __restrict__ pidx) {
  const int vt = blockIdx.x;        // 0..1999
  const int lane = threadIdx.x;     // 0..63
  const f32x4 zero = {0.f, 0.f, 0.f, 0.f};
  f32x4 aH[4] = {zero, zero, zero, zero};   // hi*hi per nb
  f32x4 aM[4] = {zero, zero, zero, zero};   // (hi*lo + lo*hi), scaled by 2048
  #pragma unroll 4
  for (int c = 0; c < 16; ++c) {
    const f16x8 wh = Wh[((size_t)vt * 16 + c) * 64 + lane];
    const f16x8 wl = Wl[((size_t)vt * 16 + c) * 64 + lane];
    #pragma unroll
    for (int nb = 0; nb < 4; ++nb) {
      const f16x8 bh = hfh[(c * 4 + nb) * 64 + lane];
      const f16x8 bl = hfl[(c * 4 + nb) * 64 + lane];
      aH[nb] = __builtin_amdgcn_mfma_f32_16x16x32_f16(wh, bh, aH[nb], 0, 0, 0);
      aM[nb] = __builtin_amdgcn_mfma_f32_16x16x32_f16(wh, bl, aM[nb], 0, 0, 0);
      aM[nb] = __builtin_amdgcn_mfma_f32_16x16x32_f16(wl, bh, aM[nb], 0, 0, 0);
    }
  }
  // epilogue: lane holds C rows v = vt*16 + (lane>>4)*4 + reg, cols b = nb*16 + (lane&15)
  const int v0 = vt * 16 + ((lane >> 4) << 2);
  const float4 bias = *(const float4*)(lb + v0);
  const float bb4[4] = {bias.x, bias.y, bias.z, bias.w};
  Part P[4];
  #pragma unroll
  for (int nb = 0; nb < 4; ++nb) {
    const int b = nb * 16 + (lane & 15);
    float lg = aH[nb][0] + aM[nb][0] * INV2048 + bb4[0];
    Part p;
    p.bv = lg + gumbel_for(k1t, k2t, (uint32_t)(b * VV + v0));
    p.bix = v0; p.blog = lg; p.m = lg; p.s = 1.0f;
    #pragma unroll
    for (int reg = 1; reg < 4; ++reg) {
      float lg2 = aH[nb][reg] + aM[nb][reg] * INV2048 + bb4[reg];
      float pe = lg2 + gumbel_for(k1t, k2t, (uint32_t)(b * VV + v0 + reg));
      if (pe > p.bv) { p.bv = pe; p.bix = v0 + reg; p.blog = lg2; }
      if (lg2 > p.m) { p.s = p.s * expf(p.m - lg2) + 1.f; p.m = lg2; }
      else           { p.s += expf(lg2 - p.m); }
    }
    P[nb] = p;
  }
  #pragma unroll
  for (int msk = 16; msk <= 32; msk <<= 1) {
    #pragma unroll
    for (int nb = 0; nb < 4; ++nb) {
      Part Q;
      Q.bv   = __shfl_xor(P[nb].bv, msk, 64);
      Q.bix  = __shfl_xor(P[nb].bix, msk, 64);
      Q.blog = __shfl_xor(P[nb].blog, msk, 64);
      Q.m    = __shfl_xor(P[nb].m, msk, 64);
      Q.s    = __shfl_xor(P[nb].s, msk, 64);
      part_combine(P[nb], Q);
    }
  }
  if (lane < 16) {
    #pragma unroll
    for (int nb = 0; nb < 4; ++nb) {
      const int b = nb * 16 + lane;
      pf4[(size_t)vt * BB + b] = make_float4(P[nb].bv, P[nb].blog, P[nb].m, P[nb].s);
      pidx[vt * BB + b] = P[nb].bix;
    }
  }
}

// ---------------- k_logits2 (mid path, r5 proven) ----------------
__global__ __launch_bounds__(128) void k_logits2(const float* __restrict__ hT,
                                                 const float* __restrict__ LW,
                                                 const float* __restrict__ lb,
                                                 uint32_t k1t, uint32_t k2t,
                                                 float4* __restrict__ pf4,
                                                 int* __restrict__ pidx) {
  const int vt = blockIdx.x;
  const int tx = threadIdx.x;
  __shared__ float lds[5120];
  float* wTs = lds;
  const int vthr = tx & 15;
  const int bthr = tx >> 4;
  const int vi = vthr * 2;
  const int bi = bthr * 8;
  const int vq = tx >> 4;
  const int ks = tx & 15;
  float acc[2][8] = {};
  for (int kt = 0; kt < 8; ++kt) {
    const int kg = kt * 64;
    #pragma unroll
    for (int s = 0; s < 4; ++s) {
      const int kk = ks + 16 * s;
      const size_t rb = (size_t)(vt * 32 + 4 * vq) * HH + kg + kk;
      float w0 = LW[rb];
      float w1 = LW[rb + HH];
      float w2 = LW[rb + 2 * HH];
      float w3 = LW[rb + 3 * HH];
      const int ph = (4 * vq) ^ (4 * (kk & 7));
      *(float4*)&wTs[kk * 32 + ph] = make_float4(w0, w1, w2, w3);
    }
    __syncthreads();
    #pragma unroll 4
    for (int kk = 0; kk < 64; ++kk) {
      const float* hrow = hT + (size_t)(kg + kk) * BB;
      const float4 h0 = *(const float4*)(hrow + bi);
      const float4 h1 = *(const float4*)(hrow + bi + 4);
      const float2 wv = *(const float2*)&wTs[kk * 32 + (vi ^ (4 * (kk & 7)))];
      acc[0][0] = fmaf(wv.x, h0.x, acc[0][0]); acc[0][1] = fmaf(wv.x, h0.y, acc[0][1]);
      acc[0][2] = fmaf(wv.x, h0.z, acc[0][2]); acc[0][3] = fmaf(wv.x, h0.w, acc[0][3]);
      acc[0][4] = fmaf(wv.x, h1.x, acc[0][4]); acc[0][5] = fmaf(wv.x, h1.y, acc[0][5]);
      acc[0][6] = fmaf(wv.x, h1.z, acc[0][6]); acc[0][7] = fmaf(wv.x, h1.w, acc[0][7]);
      acc[1][0] = fmaf(wv.y, h0.x, acc[1][0]); acc[1][1] = fmaf(wv.y, h0.y, acc[1][1]);
      acc[1][2] = fmaf(wv.y, h0.z, acc[1][2]); acc[1][3] = fmaf(wv.y, h0.w, acc[1][3]);
      acc[1][4] = fmaf(wv.y, h1.x, acc[1][4]); acc[1][5] = fmaf(wv.y, h1.y, acc[1][5]);
      acc[1][6] = fmaf(wv.y, h1.z, acc[1][6]); acc[1][7] = fmaf(wv.y, h1.w, acc[1][7]);
    }
    __syncthreads();
  }
  const int v0g = vt * 32 + vi;
  const float bias0 = lb[v0g];
  const float bias1 = lb[v0g + 1];
  float* red = lds;
  #pragma unroll
  for (int bb = 0; bb < 8; ++bb) {
    const int b = bi + bb;
    const float lg0 = acc[0][bb] + bias0;
    const float lg1 = acc[1][bb] + bias1;
    Part p;
    p.bv = lg0 + gumbel_for(k1t, k2t, (uint32_t)(b * VV + v0g));
    p.bix = v0g; p.blog = lg0;
    const float pe1 = lg1 + gumbel_for(k1t, k2t, (uint32_t)(b * VV + v0g + 1));
    if (pe1 > p.bv) { p.bv = pe1; p.bix = v0g + 1; p.blog = lg1; }
    if (lg0 >= lg1) { p.m = lg0; p.s = 1.f + expf(lg1 - lg0); }
    else            { p.m = lg1; p.s = 1.f + expf(lg0 - lg1); }
    const int slot = (b * 16 + vthr) * 5;
    red[slot + 0] = p.bv; red[slot + 1] = __int_as_float(p.bix); red[slot + 2] = p.blog;
    red[slot + 3] = p.m;  red[slot + 4] = p.s;
  }
  __syncthreads();
  if (tx < 64) {
    const int b = tx;
    Part P;
    { const int s0 = (b * 16) * 5;
      P.bv = red[s0]; P.bix = __float_as_int(red[s0 + 1]); P.blog = red[s0 + 2];
      P.m = red[s0 + 3]; P.s = red[s0 + 4]; }
    #pragma unroll
    for (int c = 1; c < 16; ++c) {
      const int s0 = (b * 16 + c) * 5;
      Part Q; Q.bv = red[s0]; Q.bix = __float_as_int(red[s0 + 1]); Q.blog = red[s0 + 2];
      Q.m = red[s0 + 3]; Q.s = red[s0 + 4];
      part_combine(P, Q);
    }
    pf4[(size_t)vt * BB + b] = make_float4(P.bv, P.blog, P.m, P.s);
    pidx[vt * BB + b] = P.bix;
  }
}

// ---------------- k_sample2: combine nvt partials, sample, record, embed-gather ----------------
__global__ __launch_bounds__(256) void k_sample2(const float4* __restrict__ pf4,
                                                 const int* __restrict__ pidx,
                                                 const float* __restrict__ embW,
                                                 int* __restrict__ done,
                                                 float* __restrict__ x,
                                                 float* __restrict__ out,
                                                 int step, int nvt) {
  const int b = blockIdx.x;
  const int tx = threadIdx.x;
  __shared__ float red[256 * 5];
  __shared__ int stok;
  Part p; p.bv = -FLT_MAX; p.bix = 0x7fffffff; p.blog = 0.f; p.m = -FLT_MAX; p.s = 0.f;
  for (int vt = tx; vt < nvt; vt += 256) {
    float4 q = pf4[(size_t)vt * BB + b];
    Part Q; Q.bv = q.x; Q.blog = q.y; Q.m = q.z; Q.s = q.w; Q.bix = pidx[vt * BB + b];
    part_combine(p, Q);
  }
  red[tx * 5 + 0] = p.bv; red[tx * 5 + 1] = __int_as_float(p.bix); red[tx * 5 + 2] = p.blog;
  red[tx * 5 + 3] = p.m;  red[tx * 5 + 4] = p.s;
  __syncthreads();
  for (int st = 128; st > 0; st >>= 1) {
    if (tx < st) {
      const int s0 = tx * 5, s1 = (tx + st) * 5;
      Part P, Q;
      P.bv = red[s0]; P.bix = __float_as_int(red[s0 + 1]); P.blog = red[s0 + 2]; P.m = red[s0 + 3]; P.s = red[s0 + 4];
      Q.bv = red[s1]; Q.bix = __float_as_int(red[s1 + 1]); Q.blog = red[s1 + 2]; Q.m = red[s1 + 3]; Q.s = red[s1 + 4];
      part_combine(P, Q);
      red[s0] = P.bv; red[s0 + 1] = __int_as_float(P.bix); red[s0 + 2] = P.blog; red[s0 + 3] = P.m; red[s0 + 4] = P.s;
    }
    __syncthreads();
  }
  if (tx == 0) {
    const int tok = __float_as_int(red[1]);
    const float blog = red[2], M = red[3], S = red[4];
    const float lp = blog - (M + logf(S));
    const int dn = done[b];
    out[b * TT + step] = dn ? 0.0f : (float)tok;
    out[BB * TT + b * TT + step] = dn ? 0.0f : lp;
    done[b] = dn | (tok == 2);
    stok = tok;
  }
  __syncthreads();
  const int tok = stok;
  for (int e = tx; e < EE; e += 256) x[b * EE + e] = embW[(size_t)tok * EE + e];
}

// ---------------- launch ----------------
extern "C" void kernel_launch(void* const* d_in, const int* in_sizes, int n_in,
                              void* d_out, int out_size, void* d_ws, size_t ws_size,
                              hipStream_t stream) {
  const float* features = (const float*)d_in[0];
  const float* embW     = (const float*)d_in[4];
  const float* Wih      = (const float*)d_in[5];
  const float* Whh      = (const float*)d_in[6];
  const float* bih      = (const float*)d_in[7];
  const float* bhh      = (const float*)d_in[8];
  const float* LW       = (const float*)d_in[9];
  const float* lb       = (const float*)d_in[10];
  float* out = (float*)d_out;

  // step keys: partitionable (foldlike) split of key(42)
  uint32_t keys[TT][2];
  for (int t = 0; t < TT; ++t) tf2x32(0u, 42u, 0u, (uint32_t)t, keys[t][0], keys[t][1]);

  float* ws = (float*)d_ws;
  float* hA = ws;                 // 32768 f
  float* hB = ws + 32768;
  float* cT = ws + 65536;
  float* x  = ws + 98304;

  if (ws_size >= (size_t)73000000) {
    // ---------------- MFMA fast path (~70 MB) ----------------
    float*  gatesP = ws + 131072;                        // 1,048,576 f
    float4* pf4    = (float4*)(ws + 1179648);            // 2000*64*4 f = 512,000 f
    int*    pidx   = (int*)(ws + 1691648);               // 128,000
    int*    done   = (int*)(ws + 1819648);               // 64
    _Float16* hfh  = (_Float16*)(ws + 1819712);          // 32,768 halves = 16,384 f
    _Float16* hfl  = (_Float16*)(ws + 1836096);          // 16,384 f
    _Float16* Whi  = (_Float16*)(ws + 1852480);          // 16,384,000 halves = 8,192,000 f
    _Float16* Wlo  = (_Float16*)(ws + 10044480);         // 8,192,000 f

    k_convW<<<dim3(8000), dim3(256), 0, stream>>>(LW, Whi, Wlo);
    k_init<<<dim3(128), dim3(256), 0, stream>>>(hA, cT, done);
    const float* hin = hA;
    float* hout = hB;
    for (int t = 0; t < TT; ++t) {
      const float* xin = (t == 0) ? features : x;
      k_gates<<<dim3(32, 8), dim3(256), 0, stream>>>(xin, hin, Wih, Whh, gatesP);
      k_lstm_update_frag<<<dim3(64), dim3(256), 0, stream>>>(gatesP, bih, bhh, cT, hout, hfh, hfl);
      k_logits3<<<dim3(2000), dim3(64), 0, stream>>>((const f16x8*)Whi, (const f16x8*)Wlo,
                                                     (const f16x8*)hfh, (const f16x8*)hfl,
                                                     lb, keys[t][0], keys[t][1], pf4, pidx);
      k_sample2<<<dim3(64), dim3(256), 0, stream>>>(pf4, pidx, embW, done, x, out, t, 2000);
      const float* tmp = hout; hout = (float*)hin; hin = tmp;
    }
  } else {
    // ---------------- mid path (r5 proven, ~6.4 MB) ----------------
    float*  gatesP = ws + 131072;
    float4* pf4    = (float4*)(ws + 131072 + 1048576);
    int*    pidx   = (int*)(ws + 131072 + 1048576 + 256000);
    int*    done   = (int*)(ws + 131072 + 1048576 + 256000 + 64000);

    k_init<<<dim3(128), dim3(256), 0, stream>>>(hA, cT, done);
    const float* hin = hA;
    float* hout = hB;
    for (int t = 0; t < TT; ++t) {
      const float* xin = (t == 0) ? features : x;
      k_gates<<<dim3(32, 8), dim3(256), 0, stream>>>(xin, hin, Wih, Whh, gatesP);
      k_lstm_update<<<dim3(64), dim3(256), 0, stream>>>(gatesP, bih, bhh, cT, hout);
      k_logits2<<<dim3(1000), dim3(128), 0, stream>>>(hout, LW, lb, keys[t][0], keys[t][1], pf4, pidx);
      k_sample2<<<dim3(64), dim3(256), 0, stream>>>(pf4, pidx, embW, done, x, out, t, 1000);
      const float* tmp = hout; hout = (float*)hin; hin = tmp;
    }
  }
}

// Round 7
// 940.352 us; speedup vs baseline: 2.5614x; 1.1821x over previous
//
#include <hip/hip_runtime.h>
#include <hip/hip_bf16.h>
#include <stdint.h>
#include <float.h>

// B=64, E=H=512, V=32000, T=20 (lengths[0]=T so max(lengths)==20 always)
#define BB 64
#define EE 512
#define HH 512
#define VV 32000
#define TT 20
#define INV2048 0.00048828125f

typedef _Float16 f16x8 __attribute__((ext_vector_type(8)));
typedef float f32x4 __attribute__((ext_vector_type(4)));

// ---------------- threefry2x32 (JAX-exact, 20 rounds) ----------------
__device__ __host__ __forceinline__ void tf2x32(uint32_t k0, uint32_t k1, uint32_t x0, uint32_t x1,
                                                uint32_t& o0, uint32_t& o1) {
  const uint32_t k2 = k0 ^ k1 ^ 0x1BD11BDAu;
  x0 += k0; x1 += k1;
#define RND(R) { x0 += x1; x1 = (x1 << R) | (x1 >> (32 - R)); x1 ^= x0; }
  RND(13) RND(15) RND(26) RND(6)
  x0 += k1; x1 += k2 + 1u;
  RND(17) RND(29) RND(16) RND(24)
  x0 += k2; x1 += k0 + 2u;
  RND(13) RND(15) RND(26) RND(6)
  x0 += k0; x1 += k1 + 3u;
  RND(17) RND(29) RND(16) RND(24)
  x0 += k1; x1 += k2 + 4u;
  RND(13) RND(15) RND(26) RND(6)
  x0 += k2; x1 += k0 + 5u;
#undef RND
  o0 = x0; o1 = x1;
}

// partitionable-threefry (JAX >= 0.5 default): bits = o0^o1 of tf(key,(0,idx));
// uniform = bitcast(0x3f800000|bits>>9)-1, 0 -> tiny; gumbel = -log(-log(u))
__device__ __forceinline__ float gumbel_for(uint32_t k1t, uint32_t k2t, uint32_t idx) {
  uint32_t o0, o1; tf2x32(k1t, k2t, 0u, idx, o0, o1);
  uint32_t bits = o0 ^ o1;
  uint32_t mant = bits >> 9;
  float f = __uint_as_float(0x3f800000u | mant) - 1.0f;
  float u = mant ? f : 1.1754943508222875e-38f;
  return -logf(-logf(u));
}

struct Part { float bv; int bix; float blog; float m; float s; };

__device__ __forceinline__ void part_combine(Part& P, const Part& Q) {
  if (Q.bv > P.bv || (Q.bv == P.bv && Q.bix < P.bix)) { P.bv = Q.bv; P.bix = Q.bix; P.blog = Q.blog; }
  if (Q.m > P.m) { P.s = P.s * expf(P.m - Q.m) + Q.s; P.m = Q.m; }
  else           { P.s += Q.s * expf(Q.m - P.m); }
}

// ---------------- K0: init ----------------
__global__ __launch_bounds__(256) void k_init(float* __restrict__ hA, float* __restrict__ cT,
                                              int* __restrict__ done) {
  int i = blockIdx.x * 256 + threadIdx.x;
  if (i < HH * BB) { hA[i] = 0.f; cT[i] = 0.f; }
  if (i < BB) done[i] = 0;
}

// ---------------- k_gates: split-k gates GEMM (proven) ----------------
__global__ __launch_bounds__(256) void k_gates(const float* __restrict__ xin,  // [64][512] b-major
                                               const float* __restrict__ hT,   // [512][64]
                                               const float* __restrict__ Wih,
                                               const float* __restrict__ Whh,
                                               float* __restrict__ gatesP) {
  const int jt = blockIdx.x;   // 0..31
  const int kc = blockIdx.y;   // 0..7
  const int tx = threadIdx.x;
  __shared__ float a[64][64];
  __shared__ float wj[64][68];
  const int bi = (tx & 15) * 4;
  const int ji = (tx >> 4) * 4;
  float acc[4][4] = {};
  const float* Wsrc = (kc < 4) ? Wih : Whh;
  for (int s = 0; s < 2; ++s) {
    const int kg = kc * 128 + s * 64;
    if (kc < 4) {
      #pragma unroll
      for (int r = 0; r < 4; ++r) {
        int fi = r * 256 + tx;
        int b = fi >> 4, k4 = (fi & 15) * 4;
        const float4 v = *(const float4*)(xin + b * EE + kg + k4);
        a[k4 + 0][b] = v.x; a[k4 + 1][b] = v.y; a[k4 + 2][b] = v.z; a[k4 + 3][b] = v.w;
      }
    } else {
      #pragma unroll
      for (int r = 0; r < 4; ++r) {
        int fi = r * 256 + tx;
        int row = fi >> 4, c4 = (fi & 15) * 4;
        *(float4*)(&a[row][c4]) = *(const float4*)(hT + (kg - 512 + row) * BB + c4);
      }
    }
    const int kcol = kg & 511;
    #pragma unroll
    for (int r = 0; r < 4; ++r) {
      int fi = r * 256 + tx;
      int j = fi >> 4, k4 = (fi & 15) * 4;
      const float4 v = *(const float4*)(Wsrc + (size_t)(jt * 64 + j) * EE + kcol + k4);
      wj[k4 + 0][j] = v.x; wj[k4 + 1][j] = v.y; wj[k4 + 2][j] = v.z; wj[k4 + 3][j] = v.w;
    }
    __syncthreads();
    #pragma unroll 8
    for (int kk = 0; kk < 64; ++kk) {
      const float4 av = *(const float4*)(&a[kk][bi]);
      const float4 wv = *(const float4*)(&wj[kk][ji]);
      const float avx[4] = {av.x, av.y, av.z, av.w};
      const float wvx[4] = {wv.x, wv.y, wv.z, wv.w};
      #pragma unroll
      for (int jj = 0; jj < 4; ++jj)
        #pragma unroll
        for (int bb = 0; bb < 4; ++bb)
          acc[jj][bb] = fmaf(wvx[jj], avx[bb], acc[jj][bb]);
    }
    __syncthreads();
  }
  #pragma unroll
  for (int jj = 0; jj < 4; ++jj) {
    float4 o = make_float4(acc[jj][0], acc[jj][1], acc[jj][2], acc[jj][3]);
    *(float4*)(gatesP + ((size_t)kc * 2048 + jt * 64 + ji + jj) * BB + bi) = o;
  }
}

// ---------------- k_lstm_update (mid path) ----------------
__global__ __launch_bounds__(256) void k_lstm_update(const float* __restrict__ gatesP,
                                                     const float* __restrict__ b_ih,
                                                     const float* __restrict__ b_hh,
                                                     float* __restrict__ cT,
                                                     float* __restrict__ hT) {
  const int blk = blockIdx.x;
  const int tx = threadIdx.x;
  const int b = tx & 63;
  const int dk = tx >> 6;
  #pragma unroll
  for (int r = 0; r < 2; ++r) {
    const int k = blk * 8 + dk + r * 4;
    float g[4];
    #pragma unroll
    for (int gi = 0; gi < 4; ++gi) {
      const int j = gi * 512 + k;
      float s = 0.f;
      #pragma unroll
      for (int kc = 0; kc < 8; ++kc) s += gatesP[((size_t)kc * 2048 + j) * BB + b];
      g[gi] = s + b_ih[j] + b_hh[j];
    }
    const float ig = 1.f / (1.f + expf(-g[0]));
    const float fg = 1.f / (1.f + expf(-g[1]));
    const float gg = tanhf(g[2]);
    const float og = 1.f / (1.f + expf(-g[3]));
    const float c = fg * cT[k * BB + b] + ig * gg;
    cT[k * BB + b] = c;
    hT[k * BB + b] = og * tanhf(c);
  }
}

// ---------------- k_lstm_update_frag: + fp16 hi/lo B-fragment writes ----------------
// B-frag layout: n=lane&15 (b%16), k = c*32 + (lane>>4)*8 + j; idx = ((c*4+nb)*64+lane)*8+j
__global__ __launch_bounds__(256) void k_lstm_update_frag(const float* __restrict__ gatesP,
                                                          const float* __restrict__ b_ih,
                                                          const float* __restrict__ b_hh,
                                                          float* __restrict__ cT,
                                                          float* __restrict__ hT,
                                                          _Float16* __restrict__ hfh,
                                                          _Float16* __restrict__ hfl) {
  const int blk = blockIdx.x;
  const int tx = threadIdx.x;
  const int b = tx & 63;
  const int dk = tx >> 6;
  #pragma unroll
  for (int r = 0; r < 2; ++r) {
    const int k = blk * 8 + dk + r * 4;
    float g[4];
    #pragma unroll
    for (int gi = 0; gi < 4; ++gi) {
      const int j = gi * 512 + k;
      float s = 0.f;
      #pragma unroll
      for (int kc = 0; kc < 8; ++kc) s += gatesP[((size_t)kc * 2048 + j) * BB + b];
      g[gi] = s + b_ih[j] + b_hh[j];
    }
    const float ig = 1.f / (1.f + expf(-g[0]));
    const float fg = 1.f / (1.f + expf(-g[1]));
    const float gg = tanhf(g[2]);
    const float og = 1.f / (1.f + expf(-g[3]));
    const float c = fg * cT[k * BB + b] + ig * gg;
    cT[k * BB + b] = c;
    const float h = og * tanhf(c);
    hT[k * BB + b] = h;
    const _Float16 hh = (_Float16)h;
    const _Float16 hl = (_Float16)((h - (float)hh) * 2048.0f);
    const int cc = k >> 5, kr = k & 31;
    const int lane = (kr >> 3) * 16 + (b & 15), j = kr & 7, nb = b >> 4;
    const int idx = ((cc * 4 + nb) * 64 + lane) * 8 + j;
    hfh[idx] = hh; hfl[idx] = hl;
  }
}

// ---------------- k_convW2: LDS-transposed, fully coalesced f32 W -> fp16 hi/lo frags ----------------
// grid (500, 8): block (bv, bk) handles v in [bv*64, bv*64+64), k in [bk*64, bk*64+64)
__global__ __launch_bounds__(256) void k_convW2(const float* __restrict__ LW,
                                                _Float16* __restrict__ Wh,
                                                _Float16* __restrict__ Wl) {
  const int bv = blockIdx.x, bk = blockIdx.y;
  const int tx = threadIdx.x;
  __shared__ float lds[64][65];
  // coalesced read 64x64 f32 tile
  #pragma unroll
  for (int r = 0; r < 4; ++r) {
    const int fi = r * 256 + tx;
    const int vl = fi >> 4, k4 = (fi & 15) * 4;
    const float4 v = *(const float4*)(LW + (size_t)(bv * 64 + vl) * HH + bk * 64 + k4);
    lds[vl][k4] = v.x; lds[vl][k4 + 1] = v.y; lds[vl][k4 + 2] = v.z; lds[vl][k4 + 3] = v.w;
  }
  __syncthreads();
  // coalesced frag-layout write: 8 frags (vbl 0..3, cl 0..1) x 64 lanes x f16x8
  #pragma unroll
  for (int r = 0; r < 2; ++r) {
    const int u = r * 256 + tx;           // 0..511
    const int frag = u >> 6;              // 0..7
    const int vbl = frag >> 1, cl = frag & 1;
    const int lane = u & 63;
    const int m = lane & 15, lh = lane >> 4;
    f16x8 hi, lo;
    #pragma unroll
    for (int j = 0; j < 8; ++j) {
      const float f = lds[vbl * 16 + m][cl * 32 + lh * 8 + j];
      const _Float16 h = (_Float16)f;
      hi[j] = h;
      lo[j] = (_Float16)((f - (float)h) * 2048.0f);
    }
    const size_t o = (((size_t)(bv * 4 + vbl) * 16 + (bk * 2 + cl)) * 64 + lane) * 8;
    *(f16x8*)(Wh + o) = hi;
    *(f16x8*)(Wl + o) = lo;
  }
}

// ---------------- k_logits4: 500 blocks x 4 waves; prefetched W, split-acc MFMA ----------------
// Wave w of block handles v-tile vt = bid*4 + w (16 v), all 64 b, full K=512.
__global__ __launch_bounds__(256) void k_logits4(const f16x8* __restrict__ Wh,
                                                 const f16x8* __restrict__ Wl,
                                                 const f16x8* __restrict__ hfh,
                                                 const f16x8* __restrict__ hfl,
                                                 const float* __restrict__ lb,
                                                 uint32_t k1t, uint32_t k2t,
                                                 float4* __restrict__ pf4,
                                                 int* __restrict__ pidx) {
  const int wv = threadIdx.x >> 6;
  const int vt = blockIdx.x * 4 + wv;     // 0..1999
  const int lane = threadIdx.x & 63;
  __shared__ float red[4][64][5];
  const f32x4 zero = {0.f, 0.f, 0.f, 0.f};
  f32x4 aH[4]  = {zero, zero, zero, zero};
  f32x4 aM1[4] = {zero, zero, zero, zero};
  f32x4 aM2[4] = {zero, zero, zero, zero};
  const size_t wbase = (size_t)vt * 16 * 64 + lane;
  f16x8 whC = Wh[wbase], wlC = Wl[wbase];
  #pragma unroll 4
  for (int c = 0; c < 16; ++c) {
    f16x8 whN, wlN;
    if (c < 15) { whN = Wh[wbase + (c + 1) * 64]; wlN = Wl[wbase + (c + 1) * 64]; }
    #pragma unroll
    for (int nb = 0; nb < 4; ++nb) {
      const f16x8 bh = hfh[(c * 4 + nb) * 64 + lane];
      const f16x8 bl = hfl[(c * 4 + nb) * 64 + lane];
      aH[nb]  = __builtin_amdgcn_mfma_f32_16x16x32_f16(whC, bh, aH[nb], 0, 0, 0);
      aM1[nb] = __builtin_amdgcn_mfma_f32_16x16x32_f16(whC, bl, aM1[nb], 0, 0, 0);
      aM2[nb] = __builtin_amdgcn_mfma_f32_16x16x32_f16(wlC, bh, aM2[nb], 0, 0, 0);
    }
    whC = whN; wlC = wlN;
  }
  // epilogue: lane holds C rows v = vt*16 + (lane>>4)*4 + reg, cols b = nb*16 + (lane&15)
  const int v0 = vt * 16 + ((lane >> 4) << 2);
  const float4 bias = *(const float4*)(lb + v0);
  const float bb4[4] = {bias.x, bias.y, bias.z, bias.w};
  Part P[4];
  #pragma unroll
  for (int nb = 0; nb < 4; ++nb) {
    const int b = nb * 16 + (lane & 15);
    float lg = aH[nb][0] + (aM1[nb][0] + aM2[nb][0]) * INV2048 + bb4[0];
    Part p;
    p.bv = lg + gumbel_for(k1t, k2t, (uint32_t)(b * VV + v0));
    p.bix = v0; p.blog = lg; p.m = lg; p.s = 1.0f;
    #pragma unroll
    for (int reg = 1; reg < 4; ++reg) {
      float lg2 = aH[nb][reg] + (aM1[nb][reg] + aM2[nb][reg]) * INV2048 + bb4[reg];
      float pe = lg2 + gumbel_for(k1t, k2t, (uint32_t)(b * VV + v0 + reg));
      if (pe > p.bv) { p.bv = pe; p.bix = v0 + reg; p.blog = lg2; }
      if (lg2 > p.m) { p.s = p.s * expf(p.m - lg2) + 1.f; p.m = lg2; }
      else           { p.s += expf(lg2 - p.m); }
    }
    P[nb] = p;
  }
  #pragma unroll
  for (int msk = 16; msk <= 32; msk <<= 1) {
    #pragma unroll
    for (int nb = 0; nb < 4; ++nb) {
      Part Q;
      Q.bv   = __shfl_xor(P[nb].bv, msk, 64);
      Q.bix  = __shfl_xor(P[nb].bix, msk, 64);
      Q.blog = __shfl_xor(P[nb].blog, msk, 64);
      Q.m    = __shfl_xor(P[nb].m, msk, 64);
      Q.s    = __shfl_xor(P[nb].s, msk, 64);
      part_combine(P[nb], Q);
    }
  }
  if (lane < 16) {
    #pragma unroll
    for (int nb = 0; nb < 4; ++nb) {
      const int b = nb * 16 + lane;
      red[wv][b][0] = P[nb].bv; red[wv][b][1] = __int_as_float(P[nb].bix);
      red[wv][b][2] = P[nb].blog; red[wv][b][3] = P[nb].m; red[wv][b][4] = P[nb].s;
    }
  }
  __syncthreads();
  // combine the block's 4 v-tiles (ascending v keeps first-lowest tie semantics)
  if (threadIdx.x < 64) {
    const int b = threadIdx.x;
    Part Pc;
    Pc.bv = red[0][b][0]; Pc.bix = __float_as_int(red[0][b][1]); Pc.blog = red[0][b][2];
    Pc.m = red[0][b][3]; Pc.s = red[0][b][4];
    #pragma unroll
    for (int w = 1; w < 4; ++w) {
      Part Q;
      Q.bv = red[w][b][0]; Q.bix = __float_as_int(red[w][b][1]); Q.blog = red[w][b][2];
      Q.m = red[w][b][3]; Q.s = red[w][b][4];
      part_combine(Pc, Q);
    }
    pf4[(size_t)blockIdx.x * BB + b] = make_float4(Pc.bv, Pc.blog, Pc.m, Pc.s);
    pidx[blockIdx.x * BB + b] = Pc.bix;
  }
}

// ---------------- k_logits2 (mid path, r5 proven) ----------------
__global__ __launch_bounds__(128) void k_logits2(const float* __restrict__ hT,
                                                 const float* __restrict__ LW,
                                                 const float* __restrict__ lb,
                                                 uint32_t k1t, uint32_t k2t,
                                                 float4* __restrict__ pf4,
                                                 int* __restrict__ pidx) {
  const int vt = blockIdx.x;
  const int tx = threadIdx.x;
  __shared__ float lds[5120];
  float* wTs = lds;
  const int vthr = tx & 15;
  const int bthr = tx >> 4;
  const int vi = vthr * 2;
  const int bi = bthr * 8;
  const int vq = tx >> 4;
  const int ks = tx & 15;
  float acc[2][8] = {};
  for (int kt = 0; kt < 8; ++kt) {
    const int kg = kt * 64;
    #pragma unroll
    for (int s = 0; s < 4; ++s) {
      const int kk = ks + 16 * s;
      const size_t rb = (size_t)(vt * 32 + 4 * vq) * HH + kg + kk;
      float w0 = LW[rb];
      float w1 = LW[rb + HH];
      float w2 = LW[rb + 2 * HH];
      float w3 = LW[rb + 3 * HH];
      const int ph = (4 * vq) ^ (4 * (kk & 7));
      *(float4*)&wTs[kk * 32 + ph] = make_float4(w0, w1, w2, w3);
    }
    __syncthreads();
    #pragma unroll 4
    for (int kk = 0; kk < 64; ++kk) {
      const float* hrow = hT + (size_t)(kg + kk) * BB;
      const float4 h0 = *(const float4*)(hrow + bi);
      const float4 h1 = *(const float4*)(hrow + bi + 4);
      const float2 wv = *(const float2*)&wTs[kk * 32 + (vi ^ (4 * (kk & 7)))];
      acc[0][0] = fmaf(wv.x, h0.x, acc[0][0]); acc[0][1] = fmaf(wv.x, h0.y, acc[0][1]);
      acc[0][2] = fmaf(wv.x, h0.z, acc[0][2]); acc[0][3] = fmaf(wv.x, h0.w, acc[0][3]);
      acc[0][4] = fmaf(wv.x, h1.x, acc[0][4]); acc[0][5] = fmaf(wv.x, h1.y, acc[0][5]);
      acc[0][6] = fmaf(wv.x, h1.z, acc[0][6]); acc[0][7] = fmaf(wv.x, h1.w, acc[0][7]);
      acc[1][0] = fmaf(wv.y, h0.x, acc[1][0]); acc[1][1] = fmaf(wv.y, h0.y, acc[1][1]);
      acc[1][2] = fmaf(wv.y, h0.z, acc[1][2]); acc[1][3] = fmaf(wv.y, h0.w, acc[1][3]);
      acc[1][4] = fmaf(wv.y, h1.x, acc[1][4]); acc[1][5] = fmaf(wv.y, h1.y, acc[1][5]);
      acc[1][6] = fmaf(wv.y, h1.z, acc[1][6]); acc[1][7] = fmaf(wv.y, h1.w, acc[1][7]);
    }
    __syncthreads();
  }
  const int v0g = vt * 32 + vi;
  const float bias0 = lb[v0g];
  const float bias1 = lb[v0g + 1];
  float* red = lds;
  #pragma unroll
  for (int bb = 0; bb < 8; ++bb) {
    const int b = bi + bb;
    const float lg0 = acc[0][bb] + bias0;
    const float lg1 = acc[1][bb] + bias1;
    Part p;
    p.bv = lg0 + gumbel_for(k1t, k2t, (uint32_t)(b * VV + v0g));
    p.bix = v0g; p.blog = lg0;
    const float pe1 = lg1 + gumbel_for(k1t, k2t, (uint32_t)(b * VV + v0g + 1));
    if (pe1 > p.bv) { p.bv = pe1; p.bix = v0g + 1; p.blog = lg1; }
    if (lg0 >= lg1) { p.m = lg0; p.s = 1.f + expf(lg1 - lg0); }
    else            { p.m = lg1; p.s = 1.f + expf(lg0 - lg1); }
    const int slot = (b * 16 + vthr) * 5;
    red[slot + 0] = p.bv; red[slot + 1] = __int_as_float(p.bix); red[slot + 2] = p.blog;
    red[slot + 3] = p.m;  red[slot + 4] = p.s;
  }
  __syncthreads();
  if (tx < 64) {
    const int b = tx;
    Part P;
    { const int s0 = (b * 16) * 5;
      P.bv = red[s0]; P.bix = __float_as_int(red[s0 + 1]); P.blog = red[s0 + 2];
      P.m = red[s0 + 3]; P.s = red[s0 + 4]; }
    #pragma unroll
    for (int c = 1; c < 16; ++c) {
      const int s0 = (b * 16 + c) * 5;
      Part Q; Q.bv = red[s0]; Q.bix = __float_as_int(red[s0 + 1]); Q.blog = red[s0 + 2];
      Q.m = red[s0 + 3]; Q.s = red[s0 + 4];
      part_combine(P, Q);
    }
    pf4[(size_t)vt * BB + b] = make_float4(P.bv, P.blog, P.m, P.s);
    pidx[vt * BB + b] = P.bix;
  }
}

// ---------------- k_sample2: combine nvt partials, sample, record, embed-gather ----------------
__global__ __launch_bounds__(256) void k_sample2(const float4* __restrict__ pf4,
                                                 const int* __restrict__ pidx,
                                                 const float* __restrict__ embW,
                                                 int* __restrict__ done,
                                                 float* __restrict__ x,
                                                 float* __restrict__ out,
                                                 int step, int nvt) {
  const int b = blockIdx.x;
  const int tx = threadIdx.x;
  __shared__ float red[256 * 5];
  __shared__ int stok;
  Part p; p.bv = -FLT_MAX; p.bix = 0x7fffffff; p.blog = 0.f; p.m = -FLT_MAX; p.s = 0.f;
  for (int vt = tx; vt < nvt; vt += 256) {
    float4 q = pf4[(size_t)vt * BB + b];
    Part Q; Q.bv = q.x; Q.blog = q.y; Q.m = q.z; Q.s = q.w; Q.bix = pidx[vt * BB + b];
    part_combine(p, Q);
  }
  red[tx * 5 + 0] = p.bv; red[tx * 5 + 1] = __int_as_float(p.bix); red[tx * 5 + 2] = p.blog;
  red[tx * 5 + 3] = p.m;  red[tx * 5 + 4] = p.s;
  __syncthreads();
  for (int st = 128; st > 0; st >>= 1) {
    if (tx < st) {
      const int s0 = tx * 5, s1 = (tx + st) * 5;
      Part P, Q;
      P.bv = red[s0]; P.bix = __float_as_int(red[s0 + 1]); P.blog = red[s0 + 2]; P.m = red[s0 + 3]; P.s = red[s0 + 4];
      Q.bv = red[s1]; Q.bix = __float_as_int(red[s1 + 1]); Q.blog = red[s1 + 2]; Q.m = red[s1 + 3]; Q.s = red[s1 + 4];
      part_combine(P, Q);
      red[s0] = P.bv; red[s0 + 1] = __int_as_float(P.bix); red[s0 + 2] = P.blog; red[s0 + 3] = P.m; red[s0 + 4] = P.s;
    }
    __syncthreads();
  }
  if (tx == 0) {
    const int tok = __float_as_int(red[1]);
    const float blog = red[2], M = red[3], S = red[4];
    const float lp = blog - (M + logf(S));
    const int dn = done[b];
    out[b * TT + step] = dn ? 0.0f : (float)tok;
    out[BB * TT + b * TT + step] = dn ? 0.0f : lp;
    done[b] = dn | (tok == 2);
    stok = tok;
  }
  __syncthreads();
  const int tok = stok;
  for (int e = tx; e < EE; e += 256) x[b * EE + e] = embW[(size_t)tok * EE + e];
}

// ---------------- launch ----------------
extern "C" void kernel_launch(void* const* d_in, const int* in_sizes, int n_in,
                              void* d_out, int out_size, void* d_ws, size_t ws_size,
                              hipStream_t stream) {
  const float* features = (const float*)d_in[0];
  const float* embW     = (const float*)d_in[4];
  const float* Wih      = (const float*)d_in[5];
  const float* Whh      = (const float*)d_in[6];
  const float* bih      = (const float*)d_in[7];
  const float* bhh      = (const float*)d_in[8];
  const float* LW       = (const float*)d_in[9];
  const float* lb       = (const float*)d_in[10];
  float* out = (float*)d_out;

  // step keys: partitionable (foldlike) split of key(42)
  uint32_t keys[TT][2];
  for (int t = 0; t < TT; ++t) tf2x32(0u, 42u, 0u, (uint32_t)t, keys[t][0], keys[t][1]);

  float* ws = (float*)d_ws;
  float* hA = ws;                 // 32768 f
  float* hB = ws + 32768;
  float* cT = ws + 65536;
  float* x  = ws + 98304;

  if (ws_size >= (size_t)73000000) {
    // ---------------- MFMA fast path (~70 MB) ----------------
    float*  gatesP = ws + 131072;                        // 1,048,576 f
    float4* pf4    = (float4*)(ws + 1179648);            // 500*64*4 f = 128,000 f (slot sized 512,000)
    int*    pidx   = (int*)(ws + 1691648);               // 32,000 (slot 128,000)
    int*    done   = (int*)(ws + 1819648);               // 64
    _Float16* hfh  = (_Float16*)(ws + 1819712);          // 16,384 f
    _Float16* hfl  = (_Float16*)(ws + 1836096);          // 16,384 f
    _Float16* Whi  = (_Float16*)(ws + 1852480);          // 8,192,000 f
    _Float16* Wlo  = (_Float16*)(ws + 10044480);         // 8,192,000 f

    k_convW2<<<dim3(500, 8), dim3(256), 0, stream>>>(LW, Whi, Wlo);
    k_init<<<dim3(128), dim3(256), 0, stream>>>(hA, cT, done);
    const float* hin = hA;
    float* hout = hB;
    for (int t = 0; t < TT; ++t) {
      const float* xin = (t == 0) ? features : x;
      k_gates<<<dim3(32, 8), dim3(256), 0, stream>>>(xin, hin, Wih, Whh, gatesP);
      k_lstm_update_frag<<<dim3(64), dim3(256), 0, stream>>>(gatesP, bih, bhh, cT, hout, hfh, hfl);
      k_logits4<<<dim3(500), dim3(256), 0, stream>>>((const f16x8*)Whi, (const f16x8*)Wlo,
                                                     (const f16x8*)hfh, (const f16x8*)hfl,
                                                     lb, keys[t][0], keys[t][1], pf4, pidx);
      k_sample2<<<dim3(64), dim3(256), 0, stream>>>(pf4, pidx, embW, done, x, out, t, 500);
      const float* tmp = hout; hout = (float*)hin; hin = tmp;
    }
  } else {
    // ---------------- mid path (r5 proven, ~6.4 MB) ----------------
    float*  gatesP = ws + 131072;
    float4* pf4    = (float4*)(ws + 131072 + 1048576);
    int*    pidx   = (int*)(ws + 131072 + 1048576 + 256000);
    int*    done   = (int*)(ws + 131072 + 1048576 + 256000 + 64000);

    k_init<<<dim3(128), dim3(256), 0, stream>>>(hA, cT, done);
    const float* hin = hA;
    float* hout = hB;
    for (int t = 0; t < TT; ++t) {
      const float* xin = (t == 0) ? features : x;
      k_gates<<<dim3(32, 8), dim3(256), 0, stream>>>(xin, hin, Wih, Whh, gatesP);
      k_lstm_update<<<dim3(64), dim3(256), 0, stream>>>(gatesP, bih, bhh, cT, hout);
      k_logits2<<<dim3(1000), dim3(128), 0, stream>>>(hout, LW, lb, keys[t][0], keys[t][1], pf4, pidx);
      k_sample2<<<dim3(64), dim3(256), 0, stream>>>(pf4, pidx, embW, done, x, out, t, 1000);
      const float* tmp = hout; hout = (float*)hin; hin = tmp;
    }
  }
}